// Round 2
// baseline (4329.042 us; speedup 1.0000x reference)
//
#include <hip/hip_runtime.h>
#include <hip/hip_bf16.h>
#include <cstdint>
#include <cstddef>

// bf16 (as ushort pair in a uint) -> two f32
__device__ __forceinline__ void cvt2(unsigned int u, float& lo, float& hi) {
    union { unsigned int i; float f; } a, b;
    a.i = u << 16;
    b.i = u & 0xffff0000u;
    lo = a.f; hi = b.f;
}
__device__ __forceinline__ float bf2f(unsigned short s) {
    union { unsigned int i; float f; } c; c.i = ((unsigned int)s) << 16;
    return c.f;
}
__device__ __forceinline__ unsigned short f2bf(float f) {
    union { float f; unsigned int i; } c; c.f = f;
    unsigned int x = c.i;
    unsigned int r = (x + 0x7fffu + ((x >> 16) & 1u)) >> 16;
    return (unsigned short)r;
}

// ---- dtype detection: low-half-as-bf16 magnitude explodes iff data is fp32 ----
__global__ __launch_bounds__(256) void detect_k(const unsigned int* __restrict__ emb,
                                                int* __restrict__ flag) {
    __shared__ unsigned int red[256];
    int t = threadIdx.x;
    unsigned int m = 0;
    for (int i = t; i < 65536; i += 256) {
        unsigned int u = emb[i];
        unsigned int lo = (u << 16) & 0x7fffffffu;   // low half as bf16 bits (abs)
        m = m > lo ? m : lo;
    }
    red[t] = m; __syncthreads();
    for (int s = 128; s > 0; s >>= 1) {
        if (t < s) red[t] = red[t] > red[t + s] ? red[t] : red[t + s];
        __syncthreads();
    }
    if (t == 0) flag[0] = (red[0] > 0x4B000000u) ? 1 : 0;  // > 2^23 => fp32 input
}

// generic input -> fp32 workspace copy (flag: 1=fp32 passthrough, 0=bf16 widen)
__global__ __launch_bounds__(256) void convert_k(const void* __restrict__ src,
                                                 float* __restrict__ dst, int n,
                                                 const int* __restrict__ flag) {
    int i = blockIdx.x * 256 + threadIdx.x;
    if (i >= n) return;
    if (flag[0]) dst[i] = ((const float*)src)[i];
    else         dst[i] = bf2f(((const unsigned short*)src)[i]);
}

__global__ __launch_bounds__(256) void deg_init_k(float* __restrict__ deg, int N) {
    int i = blockIdx.x * 256 + threadIdx.x;
    if (i < N) deg[i] = 1.0f;   // self-loop
}

__global__ __launch_bounds__(256) void deg_count_k(const int* __restrict__ dst,
                                                   float* __restrict__ deg, int E) {
    int e = blockIdx.x * 256 + threadIdx.x;
    if (e < E) atomicAdd(&deg[dst[e]], 1.0f);
}

__global__ __launch_bounds__(256) void dinv_k(const float* __restrict__ deg,
                                              float* __restrict__ dinv, int N) {
    int i = blockIdx.x * 256 + threadIdx.x;
    if (i < N) dinv[i] = 1.0f / sqrtf(deg[i]);
}

// GEMM1: h1s[n][j] = dinv[n] * sum_k embed[x_ids[n]][k] * W1[k][j]
// 32 nodes/block, 256 threads: (jg = (t&31)*8 cols) x (sg = (t>>5)*4 nodes)
// LDS: W chunk 32x256 f32 (32KB) + x tile 32x128 f32 (16KB) = 48KB
__global__ __launch_bounds__(256) void gemm1_k(
    const int* __restrict__ x_ids, const void* __restrict__ embed,
    const float* __restrict__ W1F, const float* __restrict__ dinv,
    const int* __restrict__ flag,
    float* __restrict__ h1s, float* __restrict__ agg1, int N)
{
    __shared__ float wlds[32 * 256];
    __shared__ float xlds[32 * 128];
    const int t = threadIdx.x;
    const int nb = blockIdx.x * 32;
    const int f = flag[0];

    // load x tile: 512 chunks of 8 features
    #pragma unroll
    for (int i = 0; i < 2; ++i) {
        int idx = t + 256 * i;      // 0..511
        int r = idx >> 4;           // node row 0..31
        int c = idx & 15;           // chunk of 8 feats
        int node = nb + r;
        float v[8];
        if (node < N) {
            int id = x_ids[node];
            if (f) {
                const float* er = (const float*)embed + (size_t)id * 128 + c * 8;
                float4 a = *(const float4*)er;
                float4 b = *(const float4*)(er + 4);
                v[0]=a.x; v[1]=a.y; v[2]=a.z; v[3]=a.w;
                v[4]=b.x; v[5]=b.y; v[6]=b.z; v[7]=b.w;
            } else {
                uint4 u = ((const uint4*)((const unsigned short*)embed + (size_t)id * 128))[c];
                cvt2(u.x, v[0], v[1]); cvt2(u.y, v[2], v[3]);
                cvt2(u.z, v[4], v[5]); cvt2(u.w, v[6], v[7]);
            }
        } else {
            #pragma unroll
            for (int jj = 0; jj < 8; ++jj) v[jj] = 0.0f;
        }
        float* xp = &xlds[r * 128 + c * 8];
        #pragma unroll
        for (int jj = 0; jj < 8; ++jj) xp[jj] = v[jj];
    }

    const int jg = (t & 31) * 8;
    const int sg = (t >> 5) * 4;
    float acc[4][8];
    #pragma unroll
    for (int i = 0; i < 4; ++i)
        #pragma unroll
        for (int jj = 0; jj < 8; ++jj) acc[i][jj] = 0.0f;

    for (int kb = 0; kb < 128; kb += 32) {
        __syncthreads();
        // load W1F rows kb..kb+31: 8192 floats = 2048 float4
        {
            const float4* s4 = (const float4*)(W1F + (size_t)kb * 256);
            float4* d4 = (float4*)wlds;
            #pragma unroll
            for (int i = 0; i < 8; ++i) d4[t + 256 * i] = s4[t + 256 * i];
        }
        __syncthreads();
        #pragma unroll 4
        for (int k2 = 0; k2 < 32; ++k2) {
            int k = kb + k2;
            const float* wr = &wlds[k2 * 256 + jg];
            float4 wa = *(const float4*)wr;
            float4 wb = *(const float4*)(wr + 4);
            float w[8] = {wa.x, wa.y, wa.z, wa.w, wb.x, wb.y, wb.z, wb.w};
            float xv0 = xlds[(sg + 0) * 128 + k];
            float xv1 = xlds[(sg + 1) * 128 + k];
            float xv2 = xlds[(sg + 2) * 128 + k];
            float xv3 = xlds[(sg + 3) * 128 + k];
            #pragma unroll
            for (int jj = 0; jj < 8; ++jj) {
                acc[0][jj] = fmaf(xv0, w[jj], acc[0][jj]);
                acc[1][jj] = fmaf(xv1, w[jj], acc[1][jj]);
                acc[2][jj] = fmaf(xv2, w[jj], acc[2][jj]);
                acc[3][jj] = fmaf(xv3, w[jj], acc[3][jj]);
            }
        }
    }

    #pragma unroll
    for (int i = 0; i < 4; ++i) {
        int node = nb + sg + i;
        if (node < N) {
            float dv = dinv[node];
            float4 a = make_float4(acc[i][0]*dv, acc[i][1]*dv, acc[i][2]*dv, acc[i][3]*dv);
            float4 b = make_float4(acc[i][4]*dv, acc[i][5]*dv, acc[i][6]*dv, acc[i][7]*dv);
            float* hp = &h1s[(size_t)node * 256 + jg];
            float* ap = &agg1[(size_t)node * 256 + jg];
            *(float4*)hp = a; *(float4*)(hp + 4) = b;
            *(float4*)ap = a; *(float4*)(ap + 4) = b;
        }
    }
}

// scatter1: agg1[dst][j] += h1s[src][j]; one wave per edge, 4 feats/lane (256)
__global__ __launch_bounds__(256) void scatter1_k(
    const int* __restrict__ src, const int* __restrict__ dst,
    const float* __restrict__ h1s, float* __restrict__ agg1, int E)
{
    int g = blockIdx.x * 256 + threadIdx.x;
    int e = g >> 6;
    if (e >= E) return;
    int l = g & 63;
    int s = src[e], d = dst[e];
    float4 v = *(const float4*)&h1s[(size_t)s * 256 + l * 4];
    float* p = &agg1[(size_t)d * 256 + l * 4];
    atomicAdd(p + 0, v.x); atomicAdd(p + 1, v.y);
    atomicAdd(p + 2, v.z); atomicAdd(p + 3, v.w);
}

// ln1: xout[n] = LN(relu(dinv[n]*agg1[n] + b1)) * g1 + be1   (wave/node, 4 f32/lane)
__global__ __launch_bounds__(256) void ln1_k(
    const float* __restrict__ agg1, const float* __restrict__ dinv,
    const float* __restrict__ b1, const float* __restrict__ g1,
    const float* __restrict__ be1, float* __restrict__ xout, int N)
{
    int lane = threadIdx.x & 63;
    int n = blockIdx.x * 4 + (threadIdx.x >> 6);
    if (n >= N) return;
    float dv = dinv[n];
    float4 va = *(const float4*)&agg1[(size_t)n * 256 + lane * 4];
    float4 bv = *(const float4*)&b1[lane * 4];
    float x0 = fmaxf(fmaf(va.x, dv, bv.x), 0.0f);
    float x1 = fmaxf(fmaf(va.y, dv, bv.y), 0.0f);
    float x2 = fmaxf(fmaf(va.z, dv, bv.z), 0.0f);
    float x3 = fmaxf(fmaf(va.w, dv, bv.w), 0.0f);
    float s = x0 + x1 + x2 + x3;
    float q = x0*x0 + x1*x1 + x2*x2 + x3*x3;
    #pragma unroll
    for (int off = 32; off > 0; off >>= 1) {
        s += __shfl_xor(s, off);
        q += __shfl_xor(q, off);
    }
    float mu = s * (1.0f / 256.0f);
    float var = fmaxf(q * (1.0f / 256.0f) - mu * mu, 0.0f);
    float rstd = rsqrtf(var + 1e-5f);
    float4 gv = *(const float4*)&g1[lane * 4];
    float4 ev = *(const float4*)&be1[lane * 4];
    float4 o;
    o.x = fmaf((x0 - mu) * rstd, gv.x, ev.x);
    o.y = fmaf((x1 - mu) * rstd, gv.y, ev.y);
    o.z = fmaf((x2 - mu) * rstd, gv.z, ev.z);
    o.w = fmaf((x3 - mu) * rstd, gv.w, ev.w);
    *(float4*)&xout[(size_t)n * 256 + lane * 4] = o;
}

// GEMM2: h2s[n][j] = dinv[n] * sum_k x1[n][k] * W2F[k][j]; K=256, 128 outs
// 32 nodes/block: (jg = (t&15)*8 cols) x (sg = (t>>4)*2 nodes)
// LDS: W chunk 32x128 f32 (16KB) + x tile 32x256 f32 (32KB) = 48KB
__global__ __launch_bounds__(256) void gemm2_k(
    const float* __restrict__ x1, const float* __restrict__ W2F,
    const float* __restrict__ dinv, float* __restrict__ h2s,
    float* __restrict__ agg2, int N)
{
    __shared__ float wlds[32 * 128];
    __shared__ float xlds[32 * 256];
    const int t = threadIdx.x;
    const int nb = blockIdx.x * 32;

    // x tile: 2048 float4
    #pragma unroll
    for (int i = 0; i < 8; ++i) {
        int idx = t + 256 * i;     // 0..2047
        int r = idx >> 6;          // node row 0..31
        int c = idx & 63;          // float4 chunk
        int node = nb + r;
        float4 u = make_float4(0.f, 0.f, 0.f, 0.f);
        if (node < N) u = ((const float4*)(x1 + (size_t)node * 256))[c];
        *(float4*)&xlds[r * 256 + c * 4] = u;
    }

    const int jg = (t & 15) * 8;
    const int sg = (t >> 4) * 2;
    float acc[2][8];
    #pragma unroll
    for (int i = 0; i < 2; ++i)
        #pragma unroll
        for (int jj = 0; jj < 8; ++jj) acc[i][jj] = 0.0f;

    for (int kb = 0; kb < 256; kb += 32) {
        __syncthreads();
        // load W2F rows kb..kb+31: 4096 floats = 1024 float4
        {
            const float4* s4 = (const float4*)(W2F + (size_t)kb * 128);
            float4* d4 = (float4*)wlds;
            #pragma unroll
            for (int i = 0; i < 4; ++i) d4[t + 256 * i] = s4[t + 256 * i];
        }
        __syncthreads();
        #pragma unroll 4
        for (int k2 = 0; k2 < 32; ++k2) {
            int k = kb + k2;
            const float* wr = &wlds[k2 * 128 + jg];
            float4 wa = *(const float4*)wr;
            float4 wb = *(const float4*)(wr + 4);
            float w[8] = {wa.x, wa.y, wa.z, wa.w, wb.x, wb.y, wb.z, wb.w};
            float xv0 = xlds[(sg + 0) * 256 + k];
            float xv1 = xlds[(sg + 1) * 256 + k];
            #pragma unroll
            for (int jj = 0; jj < 8; ++jj) {
                acc[0][jj] = fmaf(xv0, w[jj], acc[0][jj]);
                acc[1][jj] = fmaf(xv1, w[jj], acc[1][jj]);
            }
        }
    }

    #pragma unroll
    for (int i = 0; i < 2; ++i) {
        int node = nb + sg + i;
        if (node < N) {
            float dv = dinv[node];
            float4 a = make_float4(acc[i][0]*dv, acc[i][1]*dv, acc[i][2]*dv, acc[i][3]*dv);
            float4 b = make_float4(acc[i][4]*dv, acc[i][5]*dv, acc[i][6]*dv, acc[i][7]*dv);
            float* hp = &h2s[(size_t)node * 128 + jg];
            float* ap = &agg2[(size_t)node * 128 + jg];
            *(float4*)hp = a; *(float4*)(hp + 4) = b;
            *(float4*)ap = a; *(float4*)(ap + 4) = b;
        }
    }
}

// scatter2: agg2[dst][j] += h2s[src][j]; 32 lanes/edge, 4 feats/lane (128)
__global__ __launch_bounds__(256) void scatter2_k(
    const int* __restrict__ src, const int* __restrict__ dst,
    const float* __restrict__ h2s, float* __restrict__ agg2, int E)
{
    int g = blockIdx.x * 256 + threadIdx.x;
    int e = g >> 5;
    if (e >= E) return;
    int l = g & 31;
    int s = src[e], d = dst[e];
    float4 v = *(const float4*)&h2s[(size_t)s * 128 + l * 4];
    float* p = &agg2[(size_t)d * 128 + l * 4];
    atomicAdd(p + 0, v.x); atomicAdd(p + 1, v.y);
    atomicAdd(p + 2, v.z); atomicAdd(p + 3, v.w);
}

// ln2: out[n] = LN(dinv[n]*agg2[n] + b2) * g2 + be2; store bf16 or fp32 per flag
__global__ __launch_bounds__(256) void ln2_k(
    const float* __restrict__ agg2, const float* __restrict__ dinv,
    const float* __restrict__ b2, const float* __restrict__ g2,
    const float* __restrict__ be2, const int* __restrict__ flag,
    void* __restrict__ out, int N)
{
    int lane = threadIdx.x & 63;
    int n = blockIdx.x * 4 + (threadIdx.x >> 6);
    if (n >= N) return;
    float dv = dinv[n];
    float2 va = *(const float2*)&agg2[(size_t)n * 128 + lane * 2];
    float2 bv = *(const float2*)&b2[lane * 2];
    float x0 = fmaf(va.x, dv, bv.x);
    float x1 = fmaf(va.y, dv, bv.y);
    float s = x0 + x1;
    float q = x0*x0 + x1*x1;
    #pragma unroll
    for (int off = 32; off > 0; off >>= 1) {
        s += __shfl_xor(s, off);
        q += __shfl_xor(q, off);
    }
    float mu = s * (1.0f / 128.0f);
    float var = fmaxf(q * (1.0f / 128.0f) - mu * mu, 0.0f);
    float rstd = rsqrtf(var + 1e-5f);
    float2 gv = *(const float2*)&g2[lane * 2];
    float2 ev = *(const float2*)&be2[lane * 2];
    float o0 = fmaf((x0 - mu) * rstd, gv.x, ev.x);
    float o1 = fmaf((x1 - mu) * rstd, gv.y, ev.y);
    if (flag[0]) {
        *(float2*)&((float*)out)[(size_t)n * 128 + lane * 2] = make_float2(o0, o1);
    } else {
        unsigned int packed = (unsigned int)f2bf(o0) | ((unsigned int)f2bf(o1) << 16);
        *(unsigned int*)&((unsigned short*)out)[(size_t)n * 128 + lane * 2] = packed;
    }
}

extern "C" void kernel_launch(void* const* d_in, const int* in_sizes, int n_in,
                              void* d_out, int out_size, void* d_ws, size_t ws_size,
                              hipStream_t stream) {
    const int N = in_sizes[0];
    const int E = in_sizes[1] / 2;

    const int* x_ids = (const int*)d_in[0];
    const int* src = (const int*)d_in[1];
    const int* dst = src + E;
    const void* embed = d_in[2];
    const void* W1 = d_in[3];
    const void* b1 = d_in[4];
    const void* g1 = d_in[5];
    const void* be1 = d_in[6];
    const void* W2 = d_in[7];
    const void* b2 = d_in[8];
    const void* g2 = d_in[9];
    const void* be2 = d_in[10];

    float* base = (float*)d_ws;
    int* flag   = (int*)d_ws;                // [0..256) reserved
    float* W1F  = base + 256;                // 128*256 = 32768
    float* W2F  = W1F + 32768;               // 256*128 = 32768
    float* b1F  = W2F + 32768;               // 256
    float* g1F  = b1F + 256;
    float* be1F = g1F + 256;
    float* b2F  = be1F + 256;                // 128
    float* g2F  = b2F + 128;
    float* be2F = g2F + 128;
    float* deg  = be2F + 128;                // N
    float* dinv = deg + N;                   // N
    float* h1s  = dinv + N;                  // N*256
    float* agg1 = h1s + (size_t)N * 256;     // N*256
    float* x1   = h1s;                       // reuse after scatter1
    float* h2s  = agg1;                      // reuse after ln1 (N*128)
    float* agg2 = agg1 + (size_t)N * 128;    // N*128

    detect_k<<<1, 256, 0, stream>>>((const unsigned int*)embed, flag);

    convert_k<<<128, 256, 0, stream>>>(W1, W1F, 32768, flag);
    convert_k<<<128, 256, 0, stream>>>(W2, W2F, 32768, flag);
    convert_k<<<1, 256, 0, stream>>>(b1, b1F, 256, flag);
    convert_k<<<1, 256, 0, stream>>>(g1, g1F, 256, flag);
    convert_k<<<1, 256, 0, stream>>>(be1, be1F, 256, flag);
    convert_k<<<1, 256, 0, stream>>>(b2, b2F, 128, flag);
    convert_k<<<1, 256, 0, stream>>>(g2, g2F, 128, flag);
    convert_k<<<1, 256, 0, stream>>>(be2, be2F, 128, flag);

    deg_init_k <<<(N + 255) / 256, 256, 0, stream>>>(deg, N);
    deg_count_k<<<(E + 255) / 256, 256, 0, stream>>>(dst, deg, E);
    dinv_k     <<<(N + 255) / 256, 256, 0, stream>>>(deg, dinv, N);

    gemm1_k    <<<(N + 31) / 32, 256, 0, stream>>>(x_ids, embed, W1F, dinv, flag, h1s, agg1, N);
    scatter1_k <<<(int)(((size_t)E * 64 + 255) / 256), 256, 0, stream>>>(src, dst, h1s, agg1, E);
    ln1_k      <<<(N + 3) / 4, 256, 0, stream>>>(agg1, dinv, b1F, g1F, be1F, x1, N);

    gemm2_k    <<<(N + 31) / 32, 256, 0, stream>>>(x1, W2F, dinv, h2s, agg2, N);
    scatter2_k <<<(int)(((size_t)E * 32 + 255) / 256), 256, 0, stream>>>(src, dst, h2s, agg2, E);
    ln2_k      <<<(N + 3) / 4, 256, 0, stream>>>(agg2, dinv, b2F, g2F, be2F, flag, d_out, N);
}

// Round 3
// 570.834 us; speedup vs baseline: 7.5837x; 7.5837x over previous
//
#include <hip/hip_runtime.h>
#include <hip/hip_bf16.h>
#include <cstdint>
#include <cstddef>

// bf16 (as ushort pair in a uint) -> two f32
__device__ __forceinline__ void cvt2(unsigned int u, float& lo, float& hi) {
    union { unsigned int i; float f; } a, b;
    a.i = u << 16;
    b.i = u & 0xffff0000u;
    lo = a.f; hi = b.f;
}
__device__ __forceinline__ float bf2f(unsigned short s) {
    union { unsigned int i; float f; } c; c.i = ((unsigned int)s) << 16;
    return c.f;
}
__device__ __forceinline__ unsigned short f2bf(float f) {
    union { float f; unsigned int i; } c; c.f = f;
    unsigned int x = c.i;
    unsigned int r = (x + 0x7fffu + ((x >> 16) & 1u)) >> 16;
    return (unsigned short)r;
}

// ---- dtype detection: low-half-as-bf16 magnitude explodes iff data is fp32 ----
__global__ __launch_bounds__(256) void detect_k(const unsigned int* __restrict__ emb,
                                                int* __restrict__ flag) {
    __shared__ unsigned int red[256];
    int t = threadIdx.x;
    unsigned int m = 0;
    for (int i = t; i < 65536; i += 256) {
        unsigned int u = emb[i];
        unsigned int lo = (u << 16) & 0x7fffffffu;
        m = m > lo ? m : lo;
    }
    red[t] = m; __syncthreads();
    for (int s = 128; s > 0; s >>= 1) {
        if (t < s) red[t] = red[t] > red[t + s] ? red[t] : red[t + s];
        __syncthreads();
    }
    if (t == 0) flag[0] = (red[0] > 0x4B000000u) ? 1 : 0;  // > 2^23 => fp32 input
}

__global__ __launch_bounds__(256) void convert_k(const void* __restrict__ src,
                                                 float* __restrict__ dst, int n,
                                                 const int* __restrict__ flag) {
    int i = blockIdx.x * 256 + threadIdx.x;
    if (i >= n) return;
    if (flag[0]) dst[i] = ((const float*)src)[i];
    else         dst[i] = bf2f(((const unsigned short*)src)[i]);
}

// ---------------- CSR build ----------------
__global__ __launch_bounds__(256) void zero_k(int* __restrict__ p, int n) {
    int i = blockIdx.x * 256 + threadIdx.x;
    if (i < n) p[i] = 0;
}

__global__ __launch_bounds__(256) void hist_k(const int* __restrict__ dst,
                                              int* __restrict__ cnt, int E) {
    int e = blockIdx.x * 256 + threadIdx.x;
    if (e < E) atomicAdd(&cnt[dst[e]], 1);
}

// per-256-chunk sums
__global__ __launch_bounds__(256) void blocksum_k(const int* __restrict__ cnt,
                                                  int* __restrict__ bsum, int N) {
    __shared__ int red[256];
    int t = threadIdx.x;
    int i = blockIdx.x * 256 + t;
    red[t] = (i < N) ? cnt[i] : 0;
    __syncthreads();
    for (int s = 128; s > 0; s >>= 1) {
        if (t < s) red[t] += red[t + s];
        __syncthreads();
    }
    if (t == 0) bsum[blockIdx.x] = red[0];
}

// single-block exclusive scan of NB (<=256) chunk sums
__global__ __launch_bounds__(256) void scan1_k(const int* __restrict__ bsum,
                                               int* __restrict__ boff, int NB) {
    __shared__ int sh[256];
    int t = threadIdx.x;
    int v = (t < NB) ? bsum[t] : 0;
    sh[t] = v; __syncthreads();
    for (int o = 1; o < 256; o <<= 1) {
        int u = (t >= o) ? sh[t - o] : 0;
        __syncthreads();
        sh[t] += u;
        __syncthreads();
    }
    if (t < NB) boff[t] = sh[t] - v;   // exclusive
}

// per-chunk exclusive scan + chunk offset -> offs, and duplicate into cur
__global__ __launch_bounds__(256) void scan2_k(const int* __restrict__ cnt,
                                               const int* __restrict__ boff,
                                               int* __restrict__ offs,
                                               int* __restrict__ cur, int N) {
    __shared__ int sh[256];
    int t = threadIdx.x;
    int i = blockIdx.x * 256 + t;
    int v = (i < N) ? cnt[i] : 0;
    sh[t] = v; __syncthreads();
    for (int o = 1; o < 256; o <<= 1) {
        int u = (t >= o) ? sh[t - o] : 0;
        __syncthreads();
        sh[t] += u;
        __syncthreads();
    }
    if (i < N) {
        int excl = sh[t] - v + boff[blockIdx.x];
        offs[i] = excl;
        cur[i] = excl;
    }
}

__global__ __launch_bounds__(256) void fill_k(const int* __restrict__ src,
                                              const int* __restrict__ dst,
                                              int* __restrict__ cur,
                                              int* __restrict__ csr, int E) {
    int e = blockIdx.x * 256 + threadIdx.x;
    if (e >= E) return;
    int slot = atomicAdd(&cur[dst[e]], 1);
    csr[slot] = src[e];
}

__global__ __launch_bounds__(256) void dinv_k(const int* __restrict__ cnt,
                                              float* __restrict__ dinv, int N) {
    int i = blockIdx.x * 256 + threadIdx.x;
    if (i < N) dinv[i] = rsqrtf((float)(cnt[i] + 1));   // +1 self-loop
}

// GEMM1: h1s[n][j] = dinv[n] * sum_k embed[x_ids[n]][k] * W1[k][j]
// 32 nodes/block, 256 threads: (jg = (t&31)*8 cols) x (sg = (t>>5)*4 nodes)
__global__ __launch_bounds__(256) void gemm1_k(
    const int* __restrict__ x_ids, const void* __restrict__ embed,
    const float* __restrict__ W1F, const float* __restrict__ dinv,
    const int* __restrict__ flag, float* __restrict__ h1s, int N)
{
    __shared__ float wlds[32 * 256];
    __shared__ float xlds[32 * 128];
    const int t = threadIdx.x;
    const int nb = blockIdx.x * 32;
    const int f = flag[0];

    #pragma unroll
    for (int i = 0; i < 2; ++i) {
        int idx = t + 256 * i;
        int r = idx >> 4;
        int c = idx & 15;
        int node = nb + r;
        float v[8];
        if (node < N) {
            int id = x_ids[node];
            if (f) {
                const float* er = (const float*)embed + (size_t)id * 128 + c * 8;
                float4 a = *(const float4*)er;
                float4 b = *(const float4*)(er + 4);
                v[0]=a.x; v[1]=a.y; v[2]=a.z; v[3]=a.w;
                v[4]=b.x; v[5]=b.y; v[6]=b.z; v[7]=b.w;
            } else {
                uint4 u = ((const uint4*)((const unsigned short*)embed + (size_t)id * 128))[c];
                cvt2(u.x, v[0], v[1]); cvt2(u.y, v[2], v[3]);
                cvt2(u.z, v[4], v[5]); cvt2(u.w, v[6], v[7]);
            }
        } else {
            #pragma unroll
            for (int jj = 0; jj < 8; ++jj) v[jj] = 0.0f;
        }
        float* xp = &xlds[r * 128 + c * 8];
        #pragma unroll
        for (int jj = 0; jj < 8; ++jj) xp[jj] = v[jj];
    }

    const int jg = (t & 31) * 8;
    const int sg = (t >> 5) * 4;
    float acc[4][8];
    #pragma unroll
    for (int i = 0; i < 4; ++i)
        #pragma unroll
        for (int jj = 0; jj < 8; ++jj) acc[i][jj] = 0.0f;

    for (int kb = 0; kb < 128; kb += 32) {
        __syncthreads();
        {
            const float4* s4 = (const float4*)(W1F + (size_t)kb * 256);
            float4* d4 = (float4*)wlds;
            #pragma unroll
            for (int i = 0; i < 8; ++i) d4[t + 256 * i] = s4[t + 256 * i];
        }
        __syncthreads();
        #pragma unroll 4
        for (int k2 = 0; k2 < 32; ++k2) {
            int k = kb + k2;
            const float* wr = &wlds[k2 * 256 + jg];
            float4 wa = *(const float4*)wr;
            float4 wb = *(const float4*)(wr + 4);
            float w[8] = {wa.x, wa.y, wa.z, wa.w, wb.x, wb.y, wb.z, wb.w};
            float xv0 = xlds[(sg + 0) * 128 + k];
            float xv1 = xlds[(sg + 1) * 128 + k];
            float xv2 = xlds[(sg + 2) * 128 + k];
            float xv3 = xlds[(sg + 3) * 128 + k];
            #pragma unroll
            for (int jj = 0; jj < 8; ++jj) {
                acc[0][jj] = fmaf(xv0, w[jj], acc[0][jj]);
                acc[1][jj] = fmaf(xv1, w[jj], acc[1][jj]);
                acc[2][jj] = fmaf(xv2, w[jj], acc[2][jj]);
                acc[3][jj] = fmaf(xv3, w[jj], acc[3][jj]);
            }
        }
    }

    #pragma unroll
    for (int i = 0; i < 4; ++i) {
        int node = nb + sg + i;
        if (node < N) {
            float dv = dinv[node];
            float* hp = &h1s[(size_t)node * 256 + jg];
            *(float4*)hp = make_float4(acc[i][0]*dv, acc[i][1]*dv, acc[i][2]*dv, acc[i][3]*dv);
            *(float4*)(hp+4) = make_float4(acc[i][4]*dv, acc[i][5]*dv, acc[i][6]*dv, acc[i][7]*dv);
        }
    }
}

// fused gather-aggregate + ReLU + LN for layer 1 (256 feats, wave per node)
__global__ __launch_bounds__(256) void agg_ln1_k(
    const float* __restrict__ h1s, const int* __restrict__ offs,
    const int* __restrict__ cnt, const int* __restrict__ csr,
    const float* __restrict__ dinv, const float* __restrict__ b1,
    const float* __restrict__ g1, const float* __restrict__ be1,
    float* __restrict__ xout, int N)
{
    int lane = threadIdx.x & 63;
    int n = blockIdx.x * 4 + (threadIdx.x >> 6);
    if (n >= N) return;

    float4 acc0 = *(const float4*)&h1s[(size_t)n * 256 + lane * 4];  // self-loop
    float4 acc1 = make_float4(0.f, 0.f, 0.f, 0.f);
    int beg = offs[n];
    int end = beg + cnt[n];
    int j = beg;
    for (; j + 1 < end; j += 2) {
        int s0 = csr[j], s1 = csr[j + 1];
        float4 v0 = *(const float4*)&h1s[(size_t)s0 * 256 + lane * 4];
        float4 v1 = *(const float4*)&h1s[(size_t)s1 * 256 + lane * 4];
        acc0.x += v0.x; acc0.y += v0.y; acc0.z += v0.z; acc0.w += v0.w;
        acc1.x += v1.x; acc1.y += v1.y; acc1.z += v1.z; acc1.w += v1.w;
    }
    if (j < end) {
        int s0 = csr[j];
        float4 v0 = *(const float4*)&h1s[(size_t)s0 * 256 + lane * 4];
        acc0.x += v0.x; acc0.y += v0.y; acc0.z += v0.z; acc0.w += v0.w;
    }
    float dv = dinv[n];
    float4 bv = *(const float4*)&b1[lane * 4];
    float x0 = fmaxf(fmaf(acc0.x + acc1.x, dv, bv.x), 0.0f);
    float x1 = fmaxf(fmaf(acc0.y + acc1.y, dv, bv.y), 0.0f);
    float x2 = fmaxf(fmaf(acc0.z + acc1.z, dv, bv.z), 0.0f);
    float x3 = fmaxf(fmaf(acc0.w + acc1.w, dv, bv.w), 0.0f);
    float s = x0 + x1 + x2 + x3;
    float q = x0*x0 + x1*x1 + x2*x2 + x3*x3;
    #pragma unroll
    for (int off = 32; off > 0; off >>= 1) {
        s += __shfl_xor(s, off);
        q += __shfl_xor(q, off);
    }
    float mu = s * (1.0f / 256.0f);
    float var = fmaxf(q * (1.0f / 256.0f) - mu * mu, 0.0f);
    float rstd = rsqrtf(var + 1e-5f);
    float4 gv = *(const float4*)&g1[lane * 4];
    float4 ev = *(const float4*)&be1[lane * 4];
    float4 o;
    o.x = fmaf((x0 - mu) * rstd, gv.x, ev.x);
    o.y = fmaf((x1 - mu) * rstd, gv.y, ev.y);
    o.z = fmaf((x2 - mu) * rstd, gv.z, ev.z);
    o.w = fmaf((x3 - mu) * rstd, gv.w, ev.w);
    *(float4*)&xout[(size_t)n * 256 + lane * 4] = o;
}

// GEMM2: h2s[n][j] = dinv[n] * sum_k x1[n][k] * W2F[k][j]
__global__ __launch_bounds__(256) void gemm2_k(
    const float* __restrict__ x1, const float* __restrict__ W2F,
    const float* __restrict__ dinv, float* __restrict__ h2s, int N)
{
    __shared__ float wlds[32 * 128];
    __shared__ float xlds[32 * 256];
    const int t = threadIdx.x;
    const int nb = blockIdx.x * 32;

    #pragma unroll
    for (int i = 0; i < 8; ++i) {
        int idx = t + 256 * i;
        int r = idx >> 6;
        int c = idx & 63;
        int node = nb + r;
        float4 u = make_float4(0.f, 0.f, 0.f, 0.f);
        if (node < N) u = ((const float4*)(x1 + (size_t)node * 256))[c];
        *(float4*)&xlds[r * 256 + c * 4] = u;
    }

    const int jg = (t & 15) * 8;
    const int sg = (t >> 4) * 2;
    float acc[2][8];
    #pragma unroll
    for (int i = 0; i < 2; ++i)
        #pragma unroll
        for (int jj = 0; jj < 8; ++jj) acc[i][jj] = 0.0f;

    for (int kb = 0; kb < 256; kb += 32) {
        __syncthreads();
        {
            const float4* s4 = (const float4*)(W2F + (size_t)kb * 128);
            float4* d4 = (float4*)wlds;
            #pragma unroll
            for (int i = 0; i < 4; ++i) d4[t + 256 * i] = s4[t + 256 * i];
        }
        __syncthreads();
        #pragma unroll 4
        for (int k2 = 0; k2 < 32; ++k2) {
            int k = kb + k2;
            const float* wr = &wlds[k2 * 128 + jg];
            float4 wa = *(const float4*)wr;
            float4 wb = *(const float4*)(wr + 4);
            float w[8] = {wa.x, wa.y, wa.z, wa.w, wb.x, wb.y, wb.z, wb.w};
            float xv0 = xlds[(sg + 0) * 256 + k];
            float xv1 = xlds[(sg + 1) * 256 + k];
            #pragma unroll
            for (int jj = 0; jj < 8; ++jj) {
                acc[0][jj] = fmaf(xv0, w[jj], acc[0][jj]);
                acc[1][jj] = fmaf(xv1, w[jj], acc[1][jj]);
            }
        }
    }

    #pragma unroll
    for (int i = 0; i < 2; ++i) {
        int node = nb + sg + i;
        if (node < N) {
            float dv = dinv[node];
            float* hp = &h2s[(size_t)node * 128 + jg];
            *(float4*)hp = make_float4(acc[i][0]*dv, acc[i][1]*dv, acc[i][2]*dv, acc[i][3]*dv);
            *(float4*)(hp+4) = make_float4(acc[i][4]*dv, acc[i][5]*dv, acc[i][6]*dv, acc[i][7]*dv);
        }
    }
}

// fused gather-aggregate + LN for layer 2 (128 feats, wave per node), final store
__global__ __launch_bounds__(256) void agg_ln2_k(
    const float* __restrict__ h2s, const int* __restrict__ offs,
    const int* __restrict__ cnt, const int* __restrict__ csr,
    const float* __restrict__ dinv, const float* __restrict__ b2,
    const float* __restrict__ g2, const float* __restrict__ be2,
    const int* __restrict__ flag, void* __restrict__ out, int N)
{
    int lane = threadIdx.x & 63;
    int n = blockIdx.x * 4 + (threadIdx.x >> 6);
    if (n >= N) return;

    float2 acc0 = *(const float2*)&h2s[(size_t)n * 128 + lane * 2];  // self-loop
    float2 acc1 = make_float2(0.f, 0.f);
    int beg = offs[n];
    int end = beg + cnt[n];
    int j = beg;
    for (; j + 1 < end; j += 2) {
        int s0 = csr[j], s1 = csr[j + 1];
        float2 v0 = *(const float2*)&h2s[(size_t)s0 * 128 + lane * 2];
        float2 v1 = *(const float2*)&h2s[(size_t)s1 * 128 + lane * 2];
        acc0.x += v0.x; acc0.y += v0.y;
        acc1.x += v1.x; acc1.y += v1.y;
    }
    if (j < end) {
        int s0 = csr[j];
        float2 v0 = *(const float2*)&h2s[(size_t)s0 * 128 + lane * 2];
        acc0.x += v0.x; acc0.y += v0.y;
    }
    float dv = dinv[n];
    float2 bv = *(const float2*)&b2[lane * 2];
    float x0 = fmaf(acc0.x + acc1.x, dv, bv.x);
    float x1 = fmaf(acc0.y + acc1.y, dv, bv.y);
    float s = x0 + x1;
    float q = x0*x0 + x1*x1;
    #pragma unroll
    for (int off = 32; off > 0; off >>= 1) {
        s += __shfl_xor(s, off);
        q += __shfl_xor(q, off);
    }
    float mu = s * (1.0f / 128.0f);
    float var = fmaxf(q * (1.0f / 128.0f) - mu * mu, 0.0f);
    float rstd = rsqrtf(var + 1e-5f);
    float2 gv = *(const float2*)&g2[lane * 2];
    float2 ev = *(const float2*)&be2[lane * 2];
    float o0 = fmaf((x0 - mu) * rstd, gv.x, ev.x);
    float o1 = fmaf((x1 - mu) * rstd, gv.y, ev.y);
    if (flag[0]) {
        *(float2*)&((float*)out)[(size_t)n * 128 + lane * 2] = make_float2(o0, o1);
    } else {
        unsigned int packed = (unsigned int)f2bf(o0) | ((unsigned int)f2bf(o1) << 16);
        *(unsigned int*)&((unsigned short*)out)[(size_t)n * 128 + lane * 2] = packed;
    }
}

extern "C" void kernel_launch(void* const* d_in, const int* in_sizes, int n_in,
                              void* d_out, int out_size, void* d_ws, size_t ws_size,
                              hipStream_t stream) {
    const int N = in_sizes[0];
    const int E = in_sizes[1] / 2;
    const int NB = (N + 255) / 256;

    const int* x_ids = (const int*)d_in[0];
    const int* src = (const int*)d_in[1];
    const int* dst = src + E;
    const void* embed = d_in[2];
    const void* W1 = d_in[3];
    const void* b1 = d_in[4];
    const void* g1 = d_in[5];
    const void* be1 = d_in[6];
    const void* W2 = d_in[7];
    const void* b2 = d_in[8];
    const void* g2 = d_in[9];
    const void* be2 = d_in[10];

    float* base = (float*)d_ws;
    int* flag   = (int*)d_ws;                 // 1
    float* W1F  = base + 256;                 // 32768
    float* W2F  = W1F + 32768;                // 32768
    float* b1F  = W2F + 32768;                // 256
    float* g1F  = b1F + 256;
    float* be1F = g1F + 256;
    float* b2F  = be1F + 256;                 // 128
    float* g2F  = b2F + 128;
    float* be2F = g2F + 128;
    int* bsum   = (int*)(be2F + 128);         // NB (<=256)
    int* boff   = bsum + 256;                 // NB
    int* cnt    = boff + 256;                 // N
    int* offs   = cnt + N;                    // N
    int* cur    = offs + N;                   // N
    int* csr    = cur + N;                    // E
    float* dinv = (float*)(csr + E);          // N
    float* h1s  = dinv + N;                   // N*256
    float* x1   = h1s + (size_t)N * 256;      // N*256
    float* h2s  = h1s;                        // reuse (N*128)

    detect_k<<<1, 256, 0, stream>>>((const unsigned int*)embed, flag);

    convert_k<<<128, 256, 0, stream>>>(W1, W1F, 32768, flag);
    convert_k<<<128, 256, 0, stream>>>(W2, W2F, 32768, flag);
    convert_k<<<1, 256, 0, stream>>>(b1, b1F, 256, flag);
    convert_k<<<1, 256, 0, stream>>>(g1, g1F, 256, flag);
    convert_k<<<1, 256, 0, stream>>>(be1, be1F, 256, flag);
    convert_k<<<1, 256, 0, stream>>>(b2, b2F, 128, flag);
    convert_k<<<1, 256, 0, stream>>>(g2, g2F, 128, flag);
    convert_k<<<1, 256, 0, stream>>>(be2, be2F, 128, flag);

    // CSR build
    zero_k    <<<NB, 256, 0, stream>>>(cnt, N);
    hist_k    <<<(E + 255) / 256, 256, 0, stream>>>(dst, cnt, E);
    blocksum_k<<<NB, 256, 0, stream>>>(cnt, bsum, N);
    scan1_k   <<<1, 256, 0, stream>>>(bsum, boff, NB);
    scan2_k   <<<NB, 256, 0, stream>>>(cnt, boff, offs, cur, N);
    fill_k    <<<(E + 255) / 256, 256, 0, stream>>>(src, dst, cur, csr, E);
    dinv_k    <<<NB, 256, 0, stream>>>(cnt, dinv, N);

    // layer 1
    gemm1_k   <<<(N + 31) / 32, 256, 0, stream>>>(x_ids, embed, W1F, dinv, flag, h1s, N);
    agg_ln1_k <<<(N + 3) / 4, 256, 0, stream>>>(h1s, offs, cnt, csr, dinv, b1F, g1F, be1F, x1, N);

    // layer 2
    gemm2_k   <<<(N + 31) / 32, 256, 0, stream>>>(x1, W2F, dinv, h2s, N);
    agg_ln2_k <<<(N + 3) / 4, 256, 0, stream>>>(h2s, offs, cnt, csr, dinv, b2F, g2F, be2F, flag, d_out, N);
}

// Round 4
// 401.469 us; speedup vs baseline: 10.7830x; 1.4219x over previous
//
#include <hip/hip_runtime.h>
#include <hip/hip_bf16.h>
#include <cstdint>
#include <cstddef>

typedef short bf16x8 __attribute__((ext_vector_type(8)));   // 8 bf16 (4 VGPRs)
typedef float f32x4 __attribute__((ext_vector_type(4)));    // MFMA C/D

// bf16 pair (packed in uint) -> two f32
__device__ __forceinline__ void cvt2(unsigned int u, float& lo, float& hi) {
    union { unsigned int i; float f; } a, b;
    a.i = u << 16;
    b.i = u & 0xffff0000u;
    lo = a.f; hi = b.f;
}
__device__ __forceinline__ float bf2f(unsigned short s) {
    union { unsigned int i; float f; } c; c.i = ((unsigned int)s) << 16;
    return c.f;
}
__device__ __forceinline__ unsigned short f2bf(float f) {
    union { float f; unsigned int i; } c; c.f = f;
    unsigned int x = c.i;
    unsigned int r = (x + 0x7fffu + ((x >> 16) & 1u)) >> 16;
    return (unsigned short)r;
}

// ---- dtype detection: low-half-as-bf16 magnitude explodes iff data is fp32 ----
__global__ __launch_bounds__(256) void detect_k(const unsigned int* __restrict__ emb,
                                                int* __restrict__ flag) {
    __shared__ unsigned int red[256];
    int t = threadIdx.x;
    unsigned int m = 0;
    for (int i = t; i < 65536; i += 256) {
        unsigned int u = emb[i];
        unsigned int lo = (u << 16) & 0x7fffffffu;
        m = m > lo ? m : lo;
    }
    red[t] = m; __syncthreads();
    for (int s = 128; s > 0; s >>= 1) {
        if (t < s) red[t] = red[t] > red[t + s] ? red[t] : red[t + s];
        __syncthreads();
    }
    if (t == 0) flag[0] = (red[0] > 0x4B000000u) ? 1 : 0;  // > 2^23 => fp32 input
}

// read input element as bf16 bits regardless of stored dtype
__device__ __forceinline__ unsigned short in_bf16(const void* p, size_t i, int f) {
    if (f) return f2bf(((const float*)p)[i]);
    return ((const unsigned short*)p)[i];
}
__device__ __forceinline__ float in_f32(const void* p, size_t i, int f) {
    if (f) return ((const float*)p)[i];
    return bf2f(((const unsigned short*)p)[i]);
}

// pack W1 [128][256] into per-MFMA-fragment layout: frag (jt 0..15, kk 0..3)
// W1P[((jt*4+kk)*64 + lane)*8 + j] = W1[kk*32 + (lane>>4)*8 + j][jt*16 + (lane&15)]
__global__ __launch_bounds__(256) void pack_w1_k(const void* __restrict__ W1,
                                                 const int* __restrict__ flag,
                                                 unsigned short* __restrict__ W1P) {
    int tid = blockIdx.x * 256 + threadIdx.x;       // 0..4095
    if (tid >= 16 * 4 * 64) return;
    int lane = tid & 63, kk = (tid >> 6) & 3, jt = tid >> 8;
    int col = jt * 16 + (lane & 15);
    int k0 = kk * 32 + (lane >> 4) * 8;
    int f = flag[0];
    unsigned short v[8];
    #pragma unroll
    for (int j = 0; j < 8; ++j) v[j] = in_bf16(W1, (size_t)(k0 + j) * 256 + col, f);
    #pragma unroll
    for (int j = 0; j < 8; ++j) W1P[(size_t)tid * 8 + j] = v[j];
}

// pack W2 [256][128]: frag (jt 0..7, kk 0..7)
__global__ __launch_bounds__(256) void pack_w2_k(const void* __restrict__ W2,
                                                 const int* __restrict__ flag,
                                                 unsigned short* __restrict__ W2P) {
    int tid = blockIdx.x * 256 + threadIdx.x;       // 0..4095
    if (tid >= 8 * 8 * 64) return;
    int lane = tid & 63, kk = (tid >> 6) & 7, jt = tid >> 9;
    int col = jt * 16 + (lane & 15);
    int k0 = kk * 32 + (lane >> 4) * 8;
    int f = flag[0];
    unsigned short v[8];
    #pragma unroll
    for (int j = 0; j < 8; ++j) v[j] = in_bf16(W2, (size_t)(k0 + j) * 128 + col, f);
    #pragma unroll
    for (int j = 0; j < 8; ++j) W2P[(size_t)tid * 8 + j] = v[j];
}

// all six LN/bias vectors -> fp32 workspace
__global__ __launch_bounds__(256) void pack_params_k(
    const void* b1, const void* g1, const void* be1,
    const void* b2, const void* g2, const void* be2,
    const int* __restrict__ flag,
    float* b1F, float* g1F, float* be1F, float* b2F, float* g2F, float* be2F) {
    int t = threadIdx.x;
    int f = flag[0];
    b1F[t]  = in_f32(b1, t, f);
    g1F[t]  = in_f32(g1, t, f);
    be1F[t] = in_f32(be1, t, f);
    if (t < 128) {
        b2F[t]  = in_f32(b2, t, f);
        g2F[t]  = in_f32(g2, t, f);
        be2F[t] = in_f32(be2, t, f);
    }
}

// ---------------- CSR build ----------------
__global__ __launch_bounds__(256) void zero_k(int* __restrict__ p, int n) {
    int i = blockIdx.x * 256 + threadIdx.x;
    if (i < n) p[i] = 0;
}
__global__ __launch_bounds__(256) void hist_k(const int* __restrict__ dst,
                                              int* __restrict__ cnt, int E) {
    int e = blockIdx.x * 256 + threadIdx.x;
    if (e < E) atomicAdd(&cnt[dst[e]], 1);
}
__global__ __launch_bounds__(256) void blocksum_k(const int* __restrict__ cnt,
                                                  int* __restrict__ bsum, int N) {
    __shared__ int red[256];
    int t = threadIdx.x;
    int i = blockIdx.x * 256 + t;
    red[t] = (i < N) ? cnt[i] : 0;
    __syncthreads();
    for (int s = 128; s > 0; s >>= 1) {
        if (t < s) red[t] += red[t + s];
        __syncthreads();
    }
    if (t == 0) bsum[blockIdx.x] = red[0];
}
__global__ __launch_bounds__(256) void scan1_k(const int* __restrict__ bsum,
                                               int* __restrict__ boff, int NB) {
    __shared__ int sh[256];
    int t = threadIdx.x;
    int v = (t < NB) ? bsum[t] : 0;
    sh[t] = v; __syncthreads();
    for (int o = 1; o < 256; o <<= 1) {
        int u = (t >= o) ? sh[t - o] : 0;
        __syncthreads();
        sh[t] += u;
        __syncthreads();
    }
    if (t < NB) boff[t] = sh[t] - v;
}
__global__ __launch_bounds__(256) void scan2_k(const int* __restrict__ cnt,
                                               const int* __restrict__ boff,
                                               int* __restrict__ offs,
                                               int* __restrict__ cur, int N) {
    __shared__ int sh[256];
    int t = threadIdx.x;
    int i = blockIdx.x * 256 + t;
    int v = (i < N) ? cnt[i] : 0;
    sh[t] = v; __syncthreads();
    for (int o = 1; o < 256; o <<= 1) {
        int u = (t >= o) ? sh[t - o] : 0;
        __syncthreads();
        sh[t] += u;
        __syncthreads();
    }
    if (i < N) {
        int excl = sh[t] - v + boff[blockIdx.x];
        offs[i] = excl;
        cur[i] = excl;
    }
}
__global__ __launch_bounds__(256) void fill_k(const int* __restrict__ src,
                                              const int* __restrict__ dst,
                                              int* __restrict__ cur,
                                              int* __restrict__ csr, int E) {
    int e = blockIdx.x * 256 + threadIdx.x;
    if (e >= E) return;
    int slot = atomicAdd(&cur[dst[e]], 1);
    csr[slot] = src[e];
}
__global__ __launch_bounds__(256) void dinv_k(const int* __restrict__ cnt,
                                              float* __restrict__ dinv, int N) {
    int i = blockIdx.x * 256 + threadIdx.x;
    if (i < N) dinv[i] = rsqrtf((float)(cnt[i] + 1));
}

// GEMM1 (MFMA): h1s[n][j] = bf16( dinv[n] * sum_k embed[x_ids[n]][k] * W1[k][j] )
// block = 256 thr = 4 waves; wave w: nodes [nb + w*16, +16), all 256 cols.
// A: m=lane&15, k=quad*8+j (direct gather from embed). B: W1P fragments. No LDS.
__global__ __launch_bounds__(256) void gemm1_k(
    const int* __restrict__ x_ids, const void* __restrict__ embed,
    const unsigned short* __restrict__ W1P, const float* __restrict__ dinv,
    const int* __restrict__ flag, unsigned short* __restrict__ h1s, int N)
{
    const int t = threadIdx.x;
    const int w = t >> 6;
    const int lane = t & 63;
    const int m = lane & 15;
    const int quad = lane >> 4;
    const int nb = blockIdx.x * 64;
    const int f = flag[0];

    int node_a = nb + w * 16 + m;
    int idn = node_a < N ? node_a : N - 1;
    int id = x_ids[idn];

    bf16x8 a[4];
    if (f) {
        const float* er = (const float*)embed + (size_t)id * 128 + quad * 8;
        #pragma unroll
        for (int kk = 0; kk < 4; ++kk) {
            float4 p = *(const float4*)(er + kk * 32);
            float4 q = *(const float4*)(er + kk * 32 + 4);
            bf16x8 av;
            av[0] = (short)f2bf(p.x); av[1] = (short)f2bf(p.y);
            av[2] = (short)f2bf(p.z); av[3] = (short)f2bf(p.w);
            av[4] = (short)f2bf(q.x); av[5] = (short)f2bf(q.y);
            av[6] = (short)f2bf(q.z); av[7] = (short)f2bf(q.w);
            a[kk] = av;
        }
    } else {
        const unsigned short* er = (const unsigned short*)embed + (size_t)id * 128 + quad * 8;
        #pragma unroll
        for (int kk = 0; kk < 4; ++kk)
            a[kk] = *(const bf16x8*)(er + kk * 32);
    }

    f32x4 acc[16];
    #pragma unroll
    for (int jt = 0; jt < 16; ++jt) acc[jt] = (f32x4){0.f, 0.f, 0.f, 0.f};

    #pragma unroll
    for (int kk = 0; kk < 4; ++kk) {
        #pragma unroll
        for (int jt = 0; jt < 16; ++jt) {
            bf16x8 b = *(const bf16x8*)(W1P + ((size_t)(jt * 4 + kk) * 64 + lane) * 8);
            acc[jt] = __builtin_amdgcn_mfma_f32_16x16x32_bf16(a[kk], b, acc[jt], 0, 0, 0);
        }
    }

    float4 dv4 = *(const float4*)&dinv[nb + w * 16 + quad * 4];
    float dv[4] = {dv4.x, dv4.y, dv4.z, dv4.w};
    #pragma unroll
    for (int reg = 0; reg < 4; ++reg) {
        int node_r = nb + w * 16 + quad * 4 + reg;
        if (node_r < N) {
            unsigned short* hp = h1s + (size_t)node_r * 256 + m;
            #pragma unroll
            for (int jt = 0; jt < 16; ++jt)
                hp[jt * 16] = f2bf(acc[jt][reg] * dv[reg]);
        }
    }
}

// fused gather-aggregate + ReLU + LN layer 1: reads bf16 h1s, writes bf16 x1
__global__ __launch_bounds__(256) void agg_ln1_k(
    const unsigned short* __restrict__ h1s, const int* __restrict__ offs,
    const int* __restrict__ cnt, const int* __restrict__ csr,
    const float* __restrict__ dinv, const float* __restrict__ b1,
    const float* __restrict__ g1, const float* __restrict__ be1,
    unsigned short* __restrict__ x1, int N)
{
    int lane = threadIdx.x & 63;
    int n = blockIdx.x * 4 + (threadIdx.x >> 6);
    if (n >= N) return;

    float a0, a1, a2, a3, c0, c1, c2, c3;
    {
        uint2 r = *(const uint2*)&h1s[(size_t)n * 256 + lane * 4];
        cvt2(r.x, a0, a1); cvt2(r.y, a2, a3);
    }
    c0 = c1 = c2 = c3 = 0.f;
    int beg = offs[n];
    int end = beg + cnt[n];
    int j = beg;
    for (; j + 1 < end; j += 2) {
        int s0 = csr[j], s1 = csr[j + 1];
        uint2 r0 = *(const uint2*)&h1s[(size_t)s0 * 256 + lane * 4];
        uint2 r1 = *(const uint2*)&h1s[(size_t)s1 * 256 + lane * 4];
        float v0, v1, v2, v3, u0, u1, u2, u3;
        cvt2(r0.x, v0, v1); cvt2(r0.y, v2, v3);
        cvt2(r1.x, u0, u1); cvt2(r1.y, u2, u3);
        a0 += v0; a1 += v1; a2 += v2; a3 += v3;
        c0 += u0; c1 += u1; c2 += u2; c3 += u3;
    }
    if (j < end) {
        int s0 = csr[j];
        uint2 r0 = *(const uint2*)&h1s[(size_t)s0 * 256 + lane * 4];
        float v0, v1, v2, v3;
        cvt2(r0.x, v0, v1); cvt2(r0.y, v2, v3);
        a0 += v0; a1 += v1; a2 += v2; a3 += v3;
    }
    float dv = dinv[n];
    float4 bv = *(const float4*)&b1[lane * 4];
    float x0 = fmaxf(fmaf(a0 + c0, dv, bv.x), 0.0f);
    float x1v = fmaxf(fmaf(a1 + c1, dv, bv.y), 0.0f);
    float x2 = fmaxf(fmaf(a2 + c2, dv, bv.z), 0.0f);
    float x3 = fmaxf(fmaf(a3 + c3, dv, bv.w), 0.0f);
    float s = x0 + x1v + x2 + x3;
    float q = x0*x0 + x1v*x1v + x2*x2 + x3*x3;
    #pragma unroll
    for (int off = 32; off > 0; off >>= 1) {
        s += __shfl_xor(s, off);
        q += __shfl_xor(q, off);
    }
    float mu = s * (1.0f / 256.0f);
    float var = fmaxf(q * (1.0f / 256.0f) - mu * mu, 0.0f);
    float rstd = rsqrtf(var + 1e-5f);
    float4 gv = *(const float4*)&g1[lane * 4];
    float4 ev = *(const float4*)&be1[lane * 4];
    float o0 = fmaf((x0  - mu) * rstd, gv.x, ev.x);
    float o1 = fmaf((x1v - mu) * rstd, gv.y, ev.y);
    float o2 = fmaf((x2  - mu) * rstd, gv.z, ev.z);
    float o3 = fmaf((x3  - mu) * rstd, gv.w, ev.w);
    uint2 pk;
    pk.x = (unsigned int)f2bf(o0) | ((unsigned int)f2bf(o1) << 16);
    pk.y = (unsigned int)f2bf(o2) | ((unsigned int)f2bf(o3) << 16);
    *(uint2*)&x1[(size_t)n * 256 + lane * 4] = pk;
}

// GEMM2 (MFMA): h2s[n][j] = bf16( dinv[n] * sum_k x1[n][k] * W2[k][j] ); K=256, 128 cols
__global__ __launch_bounds__(256) void gemm2_k(
    const unsigned short* __restrict__ x1, const unsigned short* __restrict__ W2P,
    const float* __restrict__ dinv, unsigned short* __restrict__ h2s, int N)
{
    const int t = threadIdx.x;
    const int w = t >> 6;
    const int lane = t & 63;
    const int m = lane & 15;
    const int quad = lane >> 4;
    const int nb = blockIdx.x * 64;

    int node_a = nb + w * 16 + m;
    int idn = node_a < N ? node_a : N - 1;

    const unsigned short* er = x1 + (size_t)idn * 256 + quad * 8;
    bf16x8 a[8];
    #pragma unroll
    for (int kk = 0; kk < 8; ++kk)
        a[kk] = *(const bf16x8*)(er + kk * 32);

    f32x4 acc[8];
    #pragma unroll
    for (int jt = 0; jt < 8; ++jt) acc[jt] = (f32x4){0.f, 0.f, 0.f, 0.f};

    #pragma unroll
    for (int kk = 0; kk < 8; ++kk) {
        #pragma unroll
        for (int jt = 0; jt < 8; ++jt) {
            bf16x8 b = *(const bf16x8*)(W2P + ((size_t)(jt * 8 + kk) * 64 + lane) * 8);
            acc[jt] = __builtin_amdgcn_mfma_f32_16x16x32_bf16(a[kk], b, acc[jt], 0, 0, 0);
        }
    }

    float4 dv4 = *(const float4*)&dinv[nb + w * 16 + quad * 4];
    float dv[4] = {dv4.x, dv4.y, dv4.z, dv4.w};
    #pragma unroll
    for (int reg = 0; reg < 4; ++reg) {
        int node_r = nb + w * 16 + quad * 4 + reg;
        if (node_r < N) {
            unsigned short* hp = h2s + (size_t)node_r * 128 + m;
            #pragma unroll
            for (int jt = 0; jt < 8; ++jt)
                hp[jt * 16] = f2bf(acc[jt][reg] * dv[reg]);
        }
    }
}

// fused gather-aggregate + LN layer 2 (128 feats), final store per flag
__global__ __launch_bounds__(256) void agg_ln2_k(
    const unsigned short* __restrict__ h2s, const int* __restrict__ offs,
    const int* __restrict__ cnt, const int* __restrict__ csr,
    const float* __restrict__ dinv, const float* __restrict__ b2,
    const float* __restrict__ g2, const float* __restrict__ be2,
    const int* __restrict__ flag, void* __restrict__ out, int N)
{
    int lane = threadIdx.x & 63;
    int n = blockIdx.x * 4 + (threadIdx.x >> 6);
    if (n >= N) return;

    float a0, a1, c0, c1;
    {
        unsigned int r = *(const unsigned int*)&h2s[(size_t)n * 128 + lane * 2];
        cvt2(r, a0, a1);
    }
    c0 = c1 = 0.f;
    int beg = offs[n];
    int end = beg + cnt[n];
    int j = beg;
    for (; j + 1 < end; j += 2) {
        int s0 = csr[j], s1 = csr[j + 1];
        unsigned int r0 = *(const unsigned int*)&h2s[(size_t)s0 * 128 + lane * 2];
        unsigned int r1 = *(const unsigned int*)&h2s[(size_t)s1 * 128 + lane * 2];
        float v0, v1, u0, u1;
        cvt2(r0, v0, v1); cvt2(r1, u0, u1);
        a0 += v0; a1 += v1;
        c0 += u0; c1 += u1;
    }
    if (j < end) {
        int s0 = csr[j];
        unsigned int r0 = *(const unsigned int*)&h2s[(size_t)s0 * 128 + lane * 2];
        float v0, v1;
        cvt2(r0, v0, v1);
        a0 += v0; a1 += v1;
    }
    float dv = dinv[n];
    float2 bv = *(const float2*)&b2[lane * 2];
    float x0 = fmaf(a0 + c0, dv, bv.x);
    float x1 = fmaf(a1 + c1, dv, bv.y);
    float s = x0 + x1;
    float q = x0*x0 + x1*x1;
    #pragma unroll
    for (int off = 32; off > 0; off >>= 1) {
        s += __shfl_xor(s, off);
        q += __shfl_xor(q, off);
    }
    float mu = s * (1.0f / 128.0f);
    float var = fmaxf(q * (1.0f / 128.0f) - mu * mu, 0.0f);
    float rstd = rsqrtf(var + 1e-5f);
    float2 gv = *(const float2*)&g2[lane * 2];
    float2 ev = *(const float2*)&be2[lane * 2];
    float o0 = fmaf((x0 - mu) * rstd, gv.x, ev.x);
    float o1 = fmaf((x1 - mu) * rstd, gv.y, ev.y);
    if (flag[0]) {
        *(float2*)&((float*)out)[(size_t)n * 128 + lane * 2] = make_float2(o0, o1);
    } else {
        unsigned int packed = (unsigned int)f2bf(o0) | ((unsigned int)f2bf(o1) << 16);
        *(unsigned int*)&((unsigned short*)out)[(size_t)n * 128 + lane * 2] = packed;
    }
}

extern "C" void kernel_launch(void* const* d_in, const int* in_sizes, int n_in,
                              void* d_out, int out_size, void* d_ws, size_t ws_size,
                              hipStream_t stream) {
    const int N = in_sizes[0];
    const int E = in_sizes[1] / 2;
    const int NB = (N + 255) / 256;

    const int* x_ids = (const int*)d_in[0];
    const int* src = (const int*)d_in[1];
    const int* dst = src + E;
    const void* embed = d_in[2];
    const void* W1 = d_in[3];
    const void* b1 = d_in[4];
    const void* g1 = d_in[5];
    const void* be1 = d_in[6];
    const void* W2 = d_in[7];
    const void* b2 = d_in[8];
    const void* g2 = d_in[9];
    const void* be2 = d_in[10];

    char* w = (char*)d_ws;
    auto take = [&](size_t bytes) { char* p = w; w += (bytes + 255) & ~(size_t)255; return p; };
    int* flag             = (int*)take(4);
    unsigned short* W1P   = (unsigned short*)take(65536);
    unsigned short* W2P   = (unsigned short*)take(65536);
    float* b1F  = (float*)take(1024);
    float* g1F  = (float*)take(1024);
    float* be1F = (float*)take(1024);
    float* b2F  = (float*)take(512);
    float* g2F  = (float*)take(512);
    float* be2F = (float*)take(512);
    int* bsum   = (int*)take(1024);
    int* boff   = (int*)take(1024);
    int* cnt    = (int*)take((size_t)N * 4);
    int* offs   = (int*)take((size_t)N * 4);
    int* cur    = (int*)take((size_t)N * 4);
    int* csr    = (int*)take((size_t)E * 4);
    float* dinv = (float*)take(((size_t)N + 64) * 4);
    unsigned short* h1s = (unsigned short*)take((size_t)N * 256 * 2);
    unsigned short* x1  = (unsigned short*)take((size_t)N * 256 * 2);
    unsigned short* h2s = h1s;   // reuse after agg_ln1 consumed h1s

    detect_k<<<1, 256, 0, stream>>>((const unsigned int*)embed, flag);

    pack_w1_k<<<16, 256, 0, stream>>>(W1, flag, W1P);
    pack_w2_k<<<16, 256, 0, stream>>>(W2, flag, W2P);
    pack_params_k<<<1, 256, 0, stream>>>(b1, g1, be1, b2, g2, be2, flag,
                                         b1F, g1F, be1F, b2F, g2F, be2F);

    // CSR build
    zero_k    <<<NB, 256, 0, stream>>>(cnt, N);
    hist_k    <<<(E + 255) / 256, 256, 0, stream>>>(dst, cnt, E);
    blocksum_k<<<NB, 256, 0, stream>>>(cnt, bsum, N);
    scan1_k   <<<1, 256, 0, stream>>>(bsum, boff, NB);
    scan2_k   <<<NB, 256, 0, stream>>>(cnt, boff, offs, cur, N);
    fill_k    <<<(E + 255) / 256, 256, 0, stream>>>(src, dst, cur, csr, E);
    dinv_k    <<<NB, 256, 0, stream>>>(cnt, dinv, N);

    // layer 1
    gemm1_k   <<<(N + 63) / 64, 256, 0, stream>>>(x_ids, embed, W1P, dinv, flag, h1s, N);
    agg_ln1_k <<<(N + 3) / 4, 256, 0, stream>>>(h1s, offs, cnt, csr, dinv, b1F, g1F, be1F, x1, N);

    // layer 2
    gemm2_k   <<<(N + 63) / 64, 256, 0, stream>>>(x1, W2P, dinv, h2s, N);
    agg_ln2_k <<<(N + 3) / 4, 256, 0, stream>>>(h2s, offs, cnt, csr, dinv, b2F, g2F, be2F, flag, d_out, N);
}

// Round 5
// 360.137 us; speedup vs baseline: 12.0205x; 1.1148x over previous
//
#include <hip/hip_runtime.h>
#include <hip/hip_bf16.h>
#include <cstdint>
#include <cstddef>

typedef short bf16x8 __attribute__((ext_vector_type(8)));   // 8 bf16 (4 VGPRs)
typedef float f32x4 __attribute__((ext_vector_type(4)));    // MFMA C/D

__device__ __forceinline__ void cvt2(unsigned int u, float& lo, float& hi) {
    union { unsigned int i; float f; } a, b;
    a.i = u << 16;
    b.i = u & 0xffff0000u;
    lo = a.f; hi = b.f;
}
__device__ __forceinline__ float bf2f(unsigned short s) {
    union { unsigned int i; float f; } c; c.i = ((unsigned int)s) << 16;
    return c.f;
}
__device__ __forceinline__ unsigned short f2bf(float f) {
    union { float f; unsigned int i; } c; c.f = f;
    unsigned int x = c.i;
    unsigned int r = (x + 0x7fffu + ((x >> 16) & 1u)) >> 16;
    return (unsigned short)r;
}

// ---- dtype detection: low-half-as-bf16 magnitude explodes iff data is fp32 ----
__global__ __launch_bounds__(256) void detect_k(const unsigned int* __restrict__ emb,
                                                int* __restrict__ flag) {
    __shared__ unsigned int red[256];
    int t = threadIdx.x;
    unsigned int m = 0;
    for (int i = t; i < 65536; i += 256) {
        unsigned int u = emb[i];
        unsigned int lo = (u << 16) & 0x7fffffffu;
        m = m > lo ? m : lo;
    }
    red[t] = m; __syncthreads();
    for (int s = 128; s > 0; s >>= 1) {
        if (t < s) red[t] = red[t] > red[t + s] ? red[t] : red[t + s];
        __syncthreads();
    }
    if (t == 0) flag[0] = (red[0] > 0x4B000000u) ? 1 : 0;  // > 2^23 => fp32 input
}

__device__ __forceinline__ unsigned short in_bf16(const void* p, size_t i, int f) {
    if (f) return f2bf(((const float*)p)[i]);
    return ((const unsigned short*)p)[i];
}
__device__ __forceinline__ float in_f32(const void* p, size_t i, int f) {
    if (f) return ((const float*)p)[i];
    return bf2f(((const unsigned short*)p)[i]);
}

// pack W1 [128][256] into per-MFMA-fragment layout: frag (jt 0..15, kk 0..3)
__global__ __launch_bounds__(256) void pack_w1_k(const void* __restrict__ W1,
                                                 const int* __restrict__ flag,
                                                 unsigned short* __restrict__ W1P) {
    int tid = blockIdx.x * 256 + threadIdx.x;       // 0..4095
    if (tid >= 16 * 4 * 64) return;
    int lane = tid & 63, kk = (tid >> 6) & 3, jt = tid >> 8;
    int col = jt * 16 + (lane & 15);
    int k0 = kk * 32 + (lane >> 4) * 8;
    int f = flag[0];
    unsigned short v[8];
    #pragma unroll
    for (int j = 0; j < 8; ++j) v[j] = in_bf16(W1, (size_t)(k0 + j) * 256 + col, f);
    #pragma unroll
    for (int j = 0; j < 8; ++j) W1P[(size_t)tid * 8 + j] = v[j];
}

// pack W2 [256][128]: frag (jt 0..7, kk 0..7)
__global__ __launch_bounds__(256) void pack_w2_k(const void* __restrict__ W2,
                                                 const int* __restrict__ flag,
                                                 unsigned short* __restrict__ W2P) {
    int tid = blockIdx.x * 256 + threadIdx.x;       // 0..4095
    if (tid >= 8 * 8 * 64) return;
    int lane = tid & 63, kk = (tid >> 6) & 7, jt = tid >> 9;
    int col = jt * 16 + (lane & 15);
    int k0 = kk * 32 + (lane >> 4) * 8;
    int f = flag[0];
    unsigned short v[8];
    #pragma unroll
    for (int j = 0; j < 8; ++j) v[j] = in_bf16(W2, (size_t)(k0 + j) * 128 + col, f);
    #pragma unroll
    for (int j = 0; j < 8; ++j) W2P[(size_t)tid * 8 + j] = v[j];
}

__global__ __launch_bounds__(256) void pack_params_k(
    const void* b1, const void* g1, const void* be1,
    const void* b2, const void* g2, const void* be2,
    const int* __restrict__ flag,
    float* b1F, float* g1F, float* be1F, float* b2F, float* g2F, float* be2F) {
    int t = threadIdx.x;
    int f = flag[0];
    b1F[t]  = in_f32(b1, t, f);
    g1F[t]  = in_f32(g1, t, f);
    be1F[t] = in_f32(be1, t, f);
    if (t < 128) {
        b2F[t]  = in_f32(b2, t, f);
        g2F[t]  = in_f32(g2, t, f);
        be2F[t] = in_f32(be2, t, f);
    }
}

// ---------------- CSR build ----------------
__global__ __launch_bounds__(256) void zero_k(int* __restrict__ p, int n) {
    int i = blockIdx.x * 256 + threadIdx.x;
    if (i < n) p[i] = 0;
}
__global__ __launch_bounds__(256) void hist_k(const int* __restrict__ dst,
                                              int* __restrict__ cnt, int E) {
    int e = blockIdx.x * 256 + threadIdx.x;
    if (e < E) atomicAdd(&cnt[dst[e]], 1);
}
__global__ __launch_bounds__(256) void blocksum_k(const int* __restrict__ cnt,
                                                  int* __restrict__ bsum, int N) {
    __shared__ int red[256];
    int t = threadIdx.x;
    int i = blockIdx.x * 256 + t;
    red[t] = (i < N) ? cnt[i] : 0;
    __syncthreads();
    for (int s = 128; s > 0; s >>= 1) {
        if (t < s) red[t] += red[t + s];
        __syncthreads();
    }
    if (t == 0) bsum[blockIdx.x] = red[0];
}
__global__ __launch_bounds__(256) void scan1_k(const int* __restrict__ bsum,
                                               int* __restrict__ boff, int NB) {
    __shared__ int sh[256];
    int t = threadIdx.x;
    int v = (t < NB) ? bsum[t] : 0;
    sh[t] = v; __syncthreads();
    for (int o = 1; o < 256; o <<= 1) {
        int u = (t >= o) ? sh[t - o] : 0;
        __syncthreads();
        sh[t] += u;
        __syncthreads();
    }
    if (t < NB) boff[t] = sh[t] - v;
}
__global__ __launch_bounds__(256) void scan2_k(const int* __restrict__ cnt,
                                               const int* __restrict__ boff,
                                               int* __restrict__ offs,
                                               int* __restrict__ cur, int N) {
    __shared__ int sh[256];
    int t = threadIdx.x;
    int i = blockIdx.x * 256 + t;
    int v = (i < N) ? cnt[i] : 0;
    sh[t] = v; __syncthreads();
    for (int o = 1; o < 256; o <<= 1) {
        int u = (t >= o) ? sh[t - o] : 0;
        __syncthreads();
        sh[t] += u;
        __syncthreads();
    }
    if (i < N) {
        int excl = sh[t] - v + boff[blockIdx.x];
        offs[i] = excl;
        cur[i] = excl;
    }
}
__global__ __launch_bounds__(256) void fill_k(const int* __restrict__ src,
                                              const int* __restrict__ dst,
                                              int* __restrict__ cur,
                                              int* __restrict__ csr, int E) {
    int e = blockIdx.x * 256 + threadIdx.x;
    if (e >= E) return;
    int slot = atomicAdd(&cur[dst[e]], 1);
    csr[slot] = src[e];
}
__global__ __launch_bounds__(256) void dinv_k(const int* __restrict__ cnt,
                                              float* __restrict__ dinv, int N) {
    int i = blockIdx.x * 256 + threadIdx.x;
    if (i < N) dinv[i] = rsqrtf((float)(cnt[i] + 1));
}

// xs[n] = bf16(dinv[n] * embed[x_ids[n]]), 16 threads/node x 8 feats
__global__ __launch_bounds__(256) void xs_k(
    const int* __restrict__ x_ids, const void* __restrict__ embed,
    const float* __restrict__ dinv, const int* __restrict__ flag,
    unsigned short* __restrict__ xs, int N)
{
    int tid = blockIdx.x * 256 + threadIdx.x;
    int n = tid >> 4;
    int c = tid & 15;
    if (n >= N) return;
    int id = x_ids[n];
    float dv = dinv[n];
    int f = flag[0];
    float v[8];
    if (f) {
        const float* er = (const float*)embed + (size_t)id * 128 + c * 8;
        float4 a = *(const float4*)er;
        float4 b = *(const float4*)(er + 4);
        v[0]=a.x; v[1]=a.y; v[2]=a.z; v[3]=a.w;
        v[4]=b.x; v[5]=b.y; v[6]=b.z; v[7]=b.w;
    } else {
        uint4 u = *(const uint4*)((const unsigned short*)embed + (size_t)id * 128 + c * 8);
        cvt2(u.x, v[0], v[1]); cvt2(u.y, v[2], v[3]);
        cvt2(u.z, v[4], v[5]); cvt2(u.w, v[6], v[7]);
    }
    union { unsigned short s[8]; uint4 u; } o;
    #pragma unroll
    for (int j = 0; j < 8; ++j) o.s[j] = f2bf(v[j] * dv);
    *(uint4*)&xs[(size_t)n * 128 + c * 8] = o.u;
}

// agg1s[d] = xs[d] + sum_{s in N(d)} xs[s]   (wave/node, 2 feats/lane, 4-way MLP)
__global__ __launch_bounds__(256) void agg1_k(
    const unsigned short* __restrict__ xs, const int* __restrict__ offs,
    const int* __restrict__ cnt, const int* __restrict__ csr,
    unsigned short* __restrict__ agg1s, int N)
{
    int lane = threadIdx.x & 63;
    int n = blockIdx.x * 4 + (threadIdx.x >> 6);
    if (n >= N) return;

    float a0, a1, b0 = 0.f, b1 = 0.f, c0 = 0.f, c1 = 0.f, d0 = 0.f, d1 = 0.f;
    {
        unsigned int r = *(const unsigned int*)&xs[(size_t)n * 128 + lane * 2];
        cvt2(r, a0, a1);
    }
    int beg = offs[n];
    int end = beg + cnt[n];
    int j = beg;
    for (; j + 3 < end; j += 4) {
        int s0 = csr[j], s1 = csr[j+1], s2 = csr[j+2], s3 = csr[j+3];
        unsigned int r0 = *(const unsigned int*)&xs[(size_t)s0 * 128 + lane * 2];
        unsigned int r1 = *(const unsigned int*)&xs[(size_t)s1 * 128 + lane * 2];
        unsigned int r2 = *(const unsigned int*)&xs[(size_t)s2 * 128 + lane * 2];
        unsigned int r3 = *(const unsigned int*)&xs[(size_t)s3 * 128 + lane * 2];
        float v0, v1;
        cvt2(r0, v0, v1); a0 += v0; a1 += v1;
        cvt2(r1, v0, v1); b0 += v0; b1 += v1;
        cvt2(r2, v0, v1); c0 += v0; c1 += v1;
        cvt2(r3, v0, v1); d0 += v0; d1 += v1;
    }
    for (; j < end; ++j) {
        int s0 = csr[j];
        unsigned int r0 = *(const unsigned int*)&xs[(size_t)s0 * 128 + lane * 2];
        float v0, v1;
        cvt2(r0, v0, v1); a0 += v0; a1 += v1;
    }
    float o0 = (a0 + b0) + (c0 + d0);
    float o1 = (a1 + b1) + (c1 + d1);
    unsigned int pk = (unsigned int)f2bf(o0) | ((unsigned int)f2bf(o1) << 16);
    *(unsigned int*)&agg1s[(size_t)n * 128 + lane * 2] = pk;
}

// GEMM1 + bias + ReLU + LN fused: x1[n] = LN(relu(dinv[n]*(agg1s[n]@W1) + b1))
// wave w: 16 rows; A m=lane&15, k=quad*8+j+kk*32; C: col=jt*16+(lane&15), row=quad*4+reg
__global__ __launch_bounds__(256) void gemm_ln1_k(
    const unsigned short* __restrict__ agg1s, const unsigned short* __restrict__ W1P,
    const float* __restrict__ dinv, const float* __restrict__ b1,
    const float* __restrict__ g1, const float* __restrict__ be1,
    unsigned short* __restrict__ x1, int N)
{
    const int t = threadIdx.x;
    const int w = t >> 6;
    const int lane = t & 63;
    const int m = lane & 15;
    const int quad = lane >> 4;
    const int nb = blockIdx.x * 64;

    int node_a = nb + w * 16 + m;
    int idn = node_a < N ? node_a : N - 1;
    const unsigned short* er = agg1s + (size_t)idn * 128 + quad * 8;
    bf16x8 a[4];
    #pragma unroll
    for (int kk = 0; kk < 4; ++kk)
        a[kk] = *(const bf16x8*)(er + kk * 32);

    f32x4 acc[16];
    #pragma unroll
    for (int jt = 0; jt < 16; ++jt) acc[jt] = (f32x4){0.f, 0.f, 0.f, 0.f};

    #pragma unroll
    for (int kk = 0; kk < 4; ++kk) {
        #pragma unroll
        for (int jt = 0; jt < 16; ++jt) {
            bf16x8 b = *(const bf16x8*)(W1P + ((size_t)(jt * 4 + kk) * 64 + lane) * 8);
            acc[jt] = __builtin_amdgcn_mfma_f32_16x16x32_bf16(a[kk], b, acc[jt], 0, 0, 0);
        }
    }

    // per-column params for this lane's columns jt*16+m
    float bcol[16], gcol[16], ecol[16];
    #pragma unroll
    for (int jt = 0; jt < 16; ++jt) {
        bcol[jt] = b1[jt * 16 + m];
        gcol[jt] = g1[jt * 16 + m];
        ecol[jt] = be1[jt * 16 + m];
    }
    float4 dv4 = *(const float4*)&dinv[nb + w * 16 + quad * 4 < N ? nb + w * 16 + quad * 4 : 0];
    float dvr[4] = {dv4.x, dv4.y, dv4.z, dv4.w};

    #pragma unroll
    for (int reg = 0; reg < 4; ++reg) {
        int row = nb + w * 16 + quad * 4 + reg;
        float v[16];
        float s = 0.f, q = 0.f;
        #pragma unroll
        for (int jt = 0; jt < 16; ++jt) {
            float x = fmaxf(fmaf(acc[jt][reg], dvr[reg], bcol[jt]), 0.0f);
            v[jt] = x;
            s += x; q += x * x;
        }
        #pragma unroll
        for (int off = 1; off < 16; off <<= 1) {
            s += __shfl_xor(s, off);
            q += __shfl_xor(q, off);
        }
        float mu = s * (1.0f / 256.0f);
        float var = fmaxf(q * (1.0f / 256.0f) - mu * mu, 0.0f);
        float rstd = rsqrtf(var + 1e-5f);
        if (row < N) {
            unsigned short* xp = x1 + (size_t)row * 256 + m;
            #pragma unroll
            for (int jt = 0; jt < 16; ++jt)
                xp[jt * 16] = f2bf(fmaf((v[jt] - mu) * rstd, gcol[jt], ecol[jt]));
        }
    }
}

// GEMM2 (MFMA): h2s[n][j] = bf16( dinv[n] * sum_k x1[n][k] * W2[k][j] ); K=256, 128 cols
__global__ __launch_bounds__(256) void gemm2_k(
    const unsigned short* __restrict__ x1, const unsigned short* __restrict__ W2P,
    const float* __restrict__ dinv, unsigned short* __restrict__ h2s, int N)
{
    const int t = threadIdx.x;
    const int w = t >> 6;
    const int lane = t & 63;
    const int m = lane & 15;
    const int quad = lane >> 4;
    const int nb = blockIdx.x * 64;

    int node_a = nb + w * 16 + m;
    int idn = node_a < N ? node_a : N - 1;

    const unsigned short* er = x1 + (size_t)idn * 256 + quad * 8;
    bf16x8 a[8];
    #pragma unroll
    for (int kk = 0; kk < 8; ++kk)
        a[kk] = *(const bf16x8*)(er + kk * 32);

    f32x4 acc[8];
    #pragma unroll
    for (int jt = 0; jt < 8; ++jt) acc[jt] = (f32x4){0.f, 0.f, 0.f, 0.f};

    #pragma unroll
    for (int kk = 0; kk < 8; ++kk) {
        #pragma unroll
        for (int jt = 0; jt < 8; ++jt) {
            bf16x8 b = *(const bf16x8*)(W2P + ((size_t)(jt * 8 + kk) * 64 + lane) * 8);
            acc[jt] = __builtin_amdgcn_mfma_f32_16x16x32_bf16(a[kk], b, acc[jt], 0, 0, 0);
        }
    }

    int base = nb + w * 16 + quad * 4;
    float4 dv4 = *(const float4*)&dinv[base < N ? base : 0];
    float dvr[4] = {dv4.x, dv4.y, dv4.z, dv4.w};
    #pragma unroll
    for (int reg = 0; reg < 4; ++reg) {
        int node_r = base + reg;
        if (node_r < N) {
            unsigned short* hp = h2s + (size_t)node_r * 128 + m;
            #pragma unroll
            for (int jt = 0; jt < 8; ++jt)
                hp[jt * 16] = f2bf(acc[jt][reg] * dvr[reg]);
        }
    }
}

// fused gather-aggregate + LN layer 2 (128 feats, wave/node, 4-way MLP), final store
__global__ __launch_bounds__(256) void agg_ln2_k(
    const unsigned short* __restrict__ h2s, const int* __restrict__ offs,
    const int* __restrict__ cnt, const int* __restrict__ csr,
    const float* __restrict__ dinv, const float* __restrict__ b2,
    const float* __restrict__ g2, const float* __restrict__ be2,
    const int* __restrict__ flag, void* __restrict__ out, int N)
{
    int lane = threadIdx.x & 63;
    int n = blockIdx.x * 4 + (threadIdx.x >> 6);
    if (n >= N) return;

    float a0, a1, b0 = 0.f, b1v = 0.f, c0 = 0.f, c1 = 0.f, d0 = 0.f, d1 = 0.f;
    {
        unsigned int r = *(const unsigned int*)&h2s[(size_t)n * 128 + lane * 2];
        cvt2(r, a0, a1);
    }
    int beg = offs[n];
    int end = beg + cnt[n];
    int j = beg;
    for (; j + 3 < end; j += 4) {
        int s0 = csr[j], s1 = csr[j+1], s2 = csr[j+2], s3 = csr[j+3];
        unsigned int r0 = *(const unsigned int*)&h2s[(size_t)s0 * 128 + lane * 2];
        unsigned int r1 = *(const unsigned int*)&h2s[(size_t)s1 * 128 + lane * 2];
        unsigned int r2 = *(const unsigned int*)&h2s[(size_t)s2 * 128 + lane * 2];
        unsigned int r3 = *(const unsigned int*)&h2s[(size_t)s3 * 128 + lane * 2];
        float v0, v1;
        cvt2(r0, v0, v1); a0 += v0; a1 += v1;
        cvt2(r1, v0, v1); b0 += v0; b1v += v1;
        cvt2(r2, v0, v1); c0 += v0; c1 += v1;
        cvt2(r3, v0, v1); d0 += v0; d1 += v1;
    }
    for (; j < end; ++j) {
        int s0 = csr[j];
        unsigned int r0 = *(const unsigned int*)&h2s[(size_t)s0 * 128 + lane * 2];
        float v0, v1;
        cvt2(r0, v0, v1); a0 += v0; a1 += v1;
    }
    float dv = dinv[n];
    float2 bv = *(const float2*)&b2[lane * 2];
    float x0 = fmaf((a0 + b0) + (c0 + d0), dv, bv.x);
    float x1 = fmaf((a1 + b1v) + (c1 + d1), dv, bv.y);
    float s = x0 + x1;
    float q = x0*x0 + x1*x1;
    #pragma unroll
    for (int off = 32; off > 0; off >>= 1) {
        s += __shfl_xor(s, off);
        q += __shfl_xor(q, off);
    }
    float mu = s * (1.0f / 128.0f);
    float var = fmaxf(q * (1.0f / 128.0f) - mu * mu, 0.0f);
    float rstd = rsqrtf(var + 1e-5f);
    float2 gv = *(const float2*)&g2[lane * 2];
    float2 ev = *(const float2*)&be2[lane * 2];
    float o0 = fmaf((x0 - mu) * rstd, gv.x, ev.x);
    float o1 = fmaf((x1 - mu) * rstd, gv.y, ev.y);
    if (flag[0]) {
        *(float2*)&((float*)out)[(size_t)n * 128 + lane * 2] = make_float2(o0, o1);
    } else {
        unsigned int packed = (unsigned int)f2bf(o0) | ((unsigned int)f2bf(o1) << 16);
        *(unsigned int*)&((unsigned short*)out)[(size_t)n * 128 + lane * 2] = packed;
    }
}

extern "C" void kernel_launch(void* const* d_in, const int* in_sizes, int n_in,
                              void* d_out, int out_size, void* d_ws, size_t ws_size,
                              hipStream_t stream) {
    const int N = in_sizes[0];
    const int E = in_sizes[1] / 2;
    const int NB = (N + 255) / 256;

    const int* x_ids = (const int*)d_in[0];
    const int* src = (const int*)d_in[1];
    const int* dst = src + E;
    const void* embed = d_in[2];
    const void* W1 = d_in[3];
    const void* b1 = d_in[4];
    const void* g1 = d_in[5];
    const void* be1 = d_in[6];
    const void* W2 = d_in[7];
    const void* b2 = d_in[8];
    const void* g2 = d_in[9];
    const void* be2 = d_in[10];

    char* w = (char*)d_ws;
    auto take = [&](size_t bytes) { char* p = w; w += (bytes + 255) & ~(size_t)255; return p; };
    int* flag             = (int*)take(4);
    unsigned short* W1P   = (unsigned short*)take(65536);
    unsigned short* W2P   = (unsigned short*)take(65536);
    float* b1F  = (float*)take(1024);
    float* g1F  = (float*)take(1024);
    float* be1F = (float*)take(1024);
    float* b2F  = (float*)take(512);
    float* g2F  = (float*)take(512);
    float* be2F = (float*)take(512);
    int* bsum   = (int*)take(1024);
    int* boff   = (int*)take(1024);
    int* cnt    = (int*)take((size_t)N * 4);
    int* offs   = (int*)take((size_t)N * 4);
    int* cur    = (int*)take((size_t)N * 4);
    int* csr    = (int*)take((size_t)E * 4);
    float* dinv = (float*)take(((size_t)N + 64) * 4);
    unsigned short* xs    = (unsigned short*)take((size_t)N * 128 * 2);
    unsigned short* agg1s = (unsigned short*)take((size_t)N * 128 * 2);
    unsigned short* x1    = (unsigned short*)take((size_t)N * 256 * 2);
    unsigned short* h2s   = agg1s;   // reuse after gemm_ln1 consumed agg1s

    detect_k<<<1, 256, 0, stream>>>((const unsigned int*)embed, flag);

    pack_w1_k<<<16, 256, 0, stream>>>(W1, flag, W1P);
    pack_w2_k<<<16, 256, 0, stream>>>(W2, flag, W2P);
    pack_params_k<<<1, 256, 0, stream>>>(b1, g1, be1, b2, g2, be2, flag,
                                         b1F, g1F, be1F, b2F, g2F, be2F);

    // CSR build
    zero_k    <<<NB, 256, 0, stream>>>(cnt, N);
    hist_k    <<<(E + 255) / 256, 256, 0, stream>>>(dst, cnt, E);
    blocksum_k<<<NB, 256, 0, stream>>>(cnt, bsum, N);
    scan1_k   <<<1, 256, 0, stream>>>(bsum, boff, NB);
    scan2_k   <<<NB, 256, 0, stream>>>(cnt, boff, offs, cur, N);
    fill_k    <<<(E + 255) / 256, 256, 0, stream>>>(src, dst, cur, csr, E);
    dinv_k    <<<NB, 256, 0, stream>>>(cnt, dinv, N);

    // layer 1: scale -> aggregate (128 feats) -> GEMM+bias+ReLU+LN fused
    xs_k      <<<(N * 16 + 255) / 256, 256, 0, stream>>>(x_ids, embed, dinv, flag, xs, N);
    agg1_k    <<<(N + 3) / 4, 256, 0, stream>>>(xs, offs, cnt, csr, agg1s, N);
    gemm_ln1_k<<<(N + 63) / 64, 256, 0, stream>>>(agg1s, W1P, dinv, b1F, g1F, be1F, x1, N);

    // layer 2: GEMM -> aggregate + LN (final store)
    gemm2_k   <<<(N + 63) / 64, 256, 0, stream>>>(x1, W2P, dinv, h2s, N);
    agg_ln2_k <<<(N + 3) / 4, 256, 0, stream>>>(h2s, offs, cnt, csr, dinv, b2F, g2F, be2F, flag, d_out, N);
}

// Round 6
// 315.508 us; speedup vs baseline: 13.7209x; 1.1415x over previous
//
#include <hip/hip_runtime.h>
#include <hip/hip_bf16.h>
#include <cstdint>
#include <cstddef>

typedef short bf16x8 __attribute__((ext_vector_type(8)));   // 8 bf16 (4 VGPRs)
typedef float f32x4 __attribute__((ext_vector_type(4)));    // MFMA C/D

__device__ __forceinline__ void cvt2(unsigned int u, float& lo, float& hi) {
    union { unsigned int i; float f; } a, b;
    a.i = u << 16;
    b.i = u & 0xffff0000u;
    lo = a.f; hi = b.f;
}
__device__ __forceinline__ float bf2f(unsigned short s) {
    union { unsigned int i; float f; } c; c.i = ((unsigned int)s) << 16;
    return c.f;
}
__device__ __forceinline__ unsigned short f2bf(float f) {
    union { float f; unsigned int i; } c; c.f = f;
    unsigned int x = c.i;
    unsigned int r = (x + 0x7fffu + ((x >> 16) & 1u)) >> 16;
    return (unsigned short)r;
}

__global__ __launch_bounds__(64) void zero_flag_k(int* __restrict__ flag) {
    if (threadIdx.x == 0) flag[0] = 0;
}

// parallel dtype detect: low-half-as-bf16 magnitude explodes iff data is fp32
__global__ __launch_bounds__(256) void detect_k(const unsigned int* __restrict__ emb,
                                                int* __restrict__ flag) {
    __shared__ unsigned int red[256];
    int t = threadIdx.x;
    unsigned int m = 0;
    int base = blockIdx.x * 4096;
    #pragma unroll
    for (int i = 0; i < 16; ++i) {
        unsigned int u = emb[base + t + 256 * i];
        unsigned int lo = (u << 16) & 0x7fffffffu;
        m = m > lo ? m : lo;
    }
    red[t] = m; __syncthreads();
    for (int s = 128; s > 0; s >>= 1) {
        if (t < s) red[t] = red[t] > red[t + s] ? red[t] : red[t + s];
        __syncthreads();
    }
    if (t == 0 && red[0] > 0x4B000000u) atomicOr(flag, 1);   // > 2^23 => fp32
}

__device__ __forceinline__ unsigned short in_bf16(const void* p, size_t i, int f) {
    if (f) return f2bf(((const float*)p)[i]);
    return ((const unsigned short*)p)[i];
}
__device__ __forceinline__ float in_f32(const void* p, size_t i, int f) {
    if (f) return ((const float*)p)[i];
    return bf2f(((const unsigned short*)p)[i]);
}

// pack W1 [128][256] into per-MFMA-fragment layout: frag (jt 0..15, kk 0..3)
__global__ __launch_bounds__(256) void pack_w1_k(const void* __restrict__ W1,
                                                 const int* __restrict__ flag,
                                                 unsigned short* __restrict__ W1P) {
    int tid = blockIdx.x * 256 + threadIdx.x;       // 0..4095
    if (tid >= 16 * 4 * 64) return;
    int lane = tid & 63, kk = (tid >> 6) & 3, jt = tid >> 8;
    int col = jt * 16 + (lane & 15);
    int k0 = kk * 32 + (lane >> 4) * 8;
    int f = flag[0];
    unsigned short v[8];
    #pragma unroll
    for (int j = 0; j < 8; ++j) v[j] = in_bf16(W1, (size_t)(k0 + j) * 256 + col, f);
    #pragma unroll
    for (int j = 0; j < 8; ++j) W1P[(size_t)tid * 8 + j] = v[j];
}

// pack W2 [256][128]: frag (jt 0..7, kk 0..7)
__global__ __launch_bounds__(256) void pack_w2_k(const void* __restrict__ W2,
                                                 const int* __restrict__ flag,
                                                 unsigned short* __restrict__ W2P) {
    int tid = blockIdx.x * 256 + threadIdx.x;       // 0..4095
    if (tid >= 8 * 8 * 64) return;
    int lane = tid & 63, kk = (tid >> 6) & 7, jt = tid >> 9;
    int col = jt * 16 + (lane & 15);
    int k0 = kk * 32 + (lane >> 4) * 8;
    int f = flag[0];
    unsigned short v[8];
    #pragma unroll
    for (int j = 0; j < 8; ++j) v[j] = in_bf16(W2, (size_t)(k0 + j) * 128 + col, f);
    #pragma unroll
    for (int j = 0; j < 8; ++j) W2P[(size_t)tid * 8 + j] = v[j];
}

__global__ __launch_bounds__(256) void pack_params_k(
    const void* b1, const void* g1, const void* be1,
    const void* b2, const void* g2, const void* be2,
    const int* __restrict__ flag,
    float* b1F, float* g1F, float* be1F, float* b2F, float* g2F, float* be2F) {
    int t = threadIdx.x;
    int f = flag[0];
    b1F[t]  = in_f32(b1, t, f);
    g1F[t]  = in_f32(g1, t, f);
    be1F[t] = in_f32(be1, t, f);
    if (t < 128) {
        b2F[t]  = in_f32(b2, t, f);
        g2F[t]  = in_f32(g2, t, f);
        be2F[t] = in_f32(be2, t, f);
    }
}

// ---------------- CSR build ----------------
__global__ __launch_bounds__(256) void zero_k(int* __restrict__ p, int n) {
    int i = blockIdx.x * 256 + threadIdx.x;
    if (i < n) p[i] = 0;
}
__global__ __launch_bounds__(256) void hist_k(const int* __restrict__ dst,
                                              int* __restrict__ cnt, int E) {
    int e = blockIdx.x * 256 + threadIdx.x;
    if (e < E) atomicAdd(&cnt[dst[e]], 1);
}
__global__ __launch_bounds__(256) void blocksum_k(const int* __restrict__ cnt,
                                                  int* __restrict__ bsum, int N) {
    __shared__ int red[256];
    int t = threadIdx.x;
    int i = blockIdx.x * 256 + t;
    red[t] = (i < N) ? cnt[i] : 0;
    __syncthreads();
    for (int s = 128; s > 0; s >>= 1) {
        if (t < s) red[t] += red[t + s];
        __syncthreads();
    }
    if (t == 0) bsum[blockIdx.x] = red[0];
}
__global__ __launch_bounds__(256) void scan1_k(const int* __restrict__ bsum,
                                               int* __restrict__ boff, int NB) {
    __shared__ int sh[256];
    int t = threadIdx.x;
    int v = (t < NB) ? bsum[t] : 0;
    sh[t] = v; __syncthreads();
    for (int o = 1; o < 256; o <<= 1) {
        int u = (t >= o) ? sh[t - o] : 0;
        __syncthreads();
        sh[t] += u;
        __syncthreads();
    }
    if (t < NB) boff[t] = sh[t] - v;
}
// per-chunk exclusive scan + chunk offset -> offs/cur; also dinv = rsqrt(cnt+1)
__global__ __launch_bounds__(256) void scan2_k(const int* __restrict__ cnt,
                                               const int* __restrict__ boff,
                                               int* __restrict__ offs,
                                               int* __restrict__ cur,
                                               float* __restrict__ dinv, int N) {
    __shared__ int sh[256];
    int t = threadIdx.x;
    int i = blockIdx.x * 256 + t;
    int v = (i < N) ? cnt[i] : 0;
    sh[t] = v; __syncthreads();
    for (int o = 1; o < 256; o <<= 1) {
        int u = (t >= o) ? sh[t - o] : 0;
        __syncthreads();
        sh[t] += u;
        __syncthreads();
    }
    if (i < N) {
        int excl = sh[t] - v + boff[blockIdx.x];
        offs[i] = excl;
        cur[i] = excl;
        dinv[i] = rsqrtf((float)(v + 1));
    }
}
// csr entries as ushort (node ids < 65536)
__global__ __launch_bounds__(256) void fill_k(const int* __restrict__ src,
                                              const int* __restrict__ dst,
                                              int* __restrict__ cur,
                                              unsigned short* __restrict__ csr, int E) {
    int e = blockIdx.x * 256 + threadIdx.x;
    if (e >= E) return;
    int slot = atomicAdd(&cur[dst[e]], 1);
    csr[slot] = (unsigned short)src[e];
}

// xs[n] = bf16(dinv[n] * embed[x_ids[n]]), 16 threads/node x 8 feats
__global__ __launch_bounds__(256) void xs_k(
    const int* __restrict__ x_ids, const void* __restrict__ embed,
    const float* __restrict__ dinv, const int* __restrict__ flag,
    unsigned short* __restrict__ xs, int N)
{
    int tid = blockIdx.x * 256 + threadIdx.x;
    int n = tid >> 4;
    int c = tid & 15;
    if (n >= N) return;
    int id = x_ids[n];
    float dv = dinv[n];
    int f = flag[0];
    float v[8];
    if (f) {
        const float* er = (const float*)embed + (size_t)id * 128 + c * 8;
        float4 a = *(const float4*)er;
        float4 b = *(const float4*)(er + 4);
        v[0]=a.x; v[1]=a.y; v[2]=a.z; v[3]=a.w;
        v[4]=b.x; v[5]=b.y; v[6]=b.z; v[7]=b.w;
    } else {
        uint4 u = *(const uint4*)((const unsigned short*)embed + (size_t)id * 128 + c * 8);
        cvt2(u.x, v[0], v[1]); cvt2(u.y, v[2], v[3]);
        cvt2(u.z, v[4], v[5]); cvt2(u.w, v[6], v[7]);
    }
    union { unsigned short s[8]; uint4 u; } o;
    #pragma unroll
    for (int j = 0; j < 8; ++j) o.s[j] = f2bf(v[j] * dv);
    *(uint4*)&xs[(size_t)n * 128 + c * 8] = o.u;
}

// agg1s[d] = xs[d] + sum_{s in N(d)} xs[s]   (wave/node, 2 feats/lane, 4-way MLP)
__global__ __launch_bounds__(256) void agg1_k(
    const unsigned short* __restrict__ xs, const int* __restrict__ offs,
    const int* __restrict__ cnt, const unsigned short* __restrict__ csr,
    unsigned short* __restrict__ agg1s, int N)
{
    int lane = threadIdx.x & 63;
    int n = blockIdx.x * 4 + (threadIdx.x >> 6);
    if (n >= N) return;

    float a0, a1, b0 = 0.f, b1 = 0.f, c0 = 0.f, c1 = 0.f, d0 = 0.f, d1 = 0.f;
    {
        unsigned int r = *(const unsigned int*)&xs[(size_t)n * 128 + lane * 2];
        cvt2(r, a0, a1);
    }
    int beg = offs[n];
    int end = beg + cnt[n];
    int j = beg;
    for (; j + 3 < end; j += 4) {
        int s0 = csr[j], s1 = csr[j+1], s2 = csr[j+2], s3 = csr[j+3];
        unsigned int r0 = *(const unsigned int*)&xs[(size_t)s0 * 128 + lane * 2];
        unsigned int r1 = *(const unsigned int*)&xs[(size_t)s1 * 128 + lane * 2];
        unsigned int r2 = *(const unsigned int*)&xs[(size_t)s2 * 128 + lane * 2];
        unsigned int r3 = *(const unsigned int*)&xs[(size_t)s3 * 128 + lane * 2];
        float v0, v1;
        cvt2(r0, v0, v1); a0 += v0; a1 += v1;
        cvt2(r1, v0, v1); b0 += v0; b1 += v1;
        cvt2(r2, v0, v1); c0 += v0; c1 += v1;
        cvt2(r3, v0, v1); d0 += v0; d1 += v1;
    }
    for (; j < end; ++j) {
        int s0 = csr[j];
        unsigned int r0 = *(const unsigned int*)&xs[(size_t)s0 * 128 + lane * 2];
        float v0, v1;
        cvt2(r0, v0, v1); a0 += v0; a1 += v1;
    }
    float o0 = (a0 + b0) + (c0 + d0);
    float o1 = (a1 + b1) + (c1 + d1);
    unsigned int pk = (unsigned int)f2bf(o0) | ((unsigned int)f2bf(o1) << 16);
    *(unsigned int*)&agg1s[(size_t)n * 128 + lane * 2] = pk;
}

// GEMM1 + bias + ReLU + LN fused: x1[n] = LN(relu(dinv[n]*(agg1s[n]@W1) + b1))
__global__ __launch_bounds__(256) void gemm_ln1_k(
    const unsigned short* __restrict__ agg1s, const unsigned short* __restrict__ W1P,
    const float* __restrict__ dinv, const float* __restrict__ b1,
    const float* __restrict__ g1, const float* __restrict__ be1,
    unsigned short* __restrict__ x1, int N)
{
    const int t = threadIdx.x;
    const int w = t >> 6;
    const int lane = t & 63;
    const int m = lane & 15;
    const int quad = lane >> 4;
    const int nb = blockIdx.x * 64;

    int node_a = nb + w * 16 + m;
    int idn = node_a < N ? node_a : N - 1;
    const unsigned short* er = agg1s + (size_t)idn * 128 + quad * 8;
    bf16x8 a[4];
    #pragma unroll
    for (int kk = 0; kk < 4; ++kk)
        a[kk] = *(const bf16x8*)(er + kk * 32);

    f32x4 acc[16];
    #pragma unroll
    for (int jt = 0; jt < 16; ++jt) acc[jt] = (f32x4){0.f, 0.f, 0.f, 0.f};

    #pragma unroll
    for (int kk = 0; kk < 4; ++kk) {
        #pragma unroll
        for (int jt = 0; jt < 16; ++jt) {
            bf16x8 b = *(const bf16x8*)(W1P + ((size_t)(jt * 4 + kk) * 64 + lane) * 8);
            acc[jt] = __builtin_amdgcn_mfma_f32_16x16x32_bf16(a[kk], b, acc[jt], 0, 0, 0);
        }
    }

    float bcol[16], gcol[16], ecol[16];
    #pragma unroll
    for (int jt = 0; jt < 16; ++jt) {
        bcol[jt] = b1[jt * 16 + m];
        gcol[jt] = g1[jt * 16 + m];
        ecol[jt] = be1[jt * 16 + m];
    }
    int base = nb + w * 16 + quad * 4;
    float4 dv4 = *(const float4*)&dinv[base < N ? base : 0];
    float dvr[4] = {dv4.x, dv4.y, dv4.z, dv4.w};

    #pragma unroll
    for (int reg = 0; reg < 4; ++reg) {
        int row = base + reg;
        float v[16];
        float s = 0.f, q = 0.f;
        #pragma unroll
        for (int jt = 0; jt < 16; ++jt) {
            float x = fmaxf(fmaf(acc[jt][reg], dvr[reg], bcol[jt]), 0.0f);
            v[jt] = x;
            s += x; q += x * x;
        }
        #pragma unroll
        for (int off = 1; off < 16; off <<= 1) {
            s += __shfl_xor(s, off);
            q += __shfl_xor(q, off);
        }
        float mu = s * (1.0f / 256.0f);
        float var = fmaxf(q * (1.0f / 256.0f) - mu * mu, 0.0f);
        float rstd = rsqrtf(var + 1e-5f);
        if (row < N) {
            unsigned short* xp = x1 + (size_t)row * 256 + m;
            #pragma unroll
            for (int jt = 0; jt < 16; ++jt)
                xp[jt * 16] = f2bf(fmaf((v[jt] - mu) * rstd, gcol[jt], ecol[jt]));
        }
    }
}

// GEMM2 (MFMA): h2s[n][j] = bf16( dinv[n] * sum_k x1[n][k] * W2[k][j] )
__global__ __launch_bounds__(256) void gemm2_k(
    const unsigned short* __restrict__ x1, const unsigned short* __restrict__ W2P,
    const float* __restrict__ dinv, unsigned short* __restrict__ h2s, int N)
{
    const int t = threadIdx.x;
    const int w = t >> 6;
    const int lane = t & 63;
    const int m = lane & 15;
    const int quad = lane >> 4;
    const int nb = blockIdx.x * 64;

    int node_a = nb + w * 16 + m;
    int idn = node_a < N ? node_a : N - 1;

    const unsigned short* er = x1 + (size_t)idn * 256 + quad * 8;
    bf16x8 a[8];
    #pragma unroll
    for (int kk = 0; kk < 8; ++kk)
        a[kk] = *(const bf16x8*)(er + kk * 32);

    f32x4 acc[8];
    #pragma unroll
    for (int jt = 0; jt < 8; ++jt) acc[jt] = (f32x4){0.f, 0.f, 0.f, 0.f};

    #pragma unroll
    for (int kk = 0; kk < 8; ++kk) {
        #pragma unroll
        for (int jt = 0; jt < 8; ++jt) {
            bf16x8 b = *(const bf16x8*)(W2P + ((size_t)(jt * 8 + kk) * 64 + lane) * 8);
            acc[jt] = __builtin_amdgcn_mfma_f32_16x16x32_bf16(a[kk], b, acc[jt], 0, 0, 0);
        }
    }

    int base = nb + w * 16 + quad * 4;
    float4 dv4 = *(const float4*)&dinv[base < N ? base : 0];
    float dvr[4] = {dv4.x, dv4.y, dv4.z, dv4.w};
    #pragma unroll
    for (int reg = 0; reg < 4; ++reg) {
        int node_r = base + reg;
        if (node_r < N) {
            unsigned short* hp = h2s + (size_t)node_r * 128 + m;
            #pragma unroll
            for (int jt = 0; jt < 8; ++jt)
                hp[jt * 16] = f2bf(acc[jt][reg] * dvr[reg]);
        }
    }
}

// fused gather-aggregate + LN layer 2 (128 feats, wave/node, 4-way MLP), final store
__global__ __launch_bounds__(256) void agg_ln2_k(
    const unsigned short* __restrict__ h2s, const int* __restrict__ offs,
    const int* __restrict__ cnt, const unsigned short* __restrict__ csr,
    const float* __restrict__ dinv, const float* __restrict__ b2,
    const float* __restrict__ g2, const float* __restrict__ be2,
    const int* __restrict__ flag, void* __restrict__ out, int N)
{
    int lane = threadIdx.x & 63;
    int n = blockIdx.x * 4 + (threadIdx.x >> 6);
    if (n >= N) return;

    float a0, a1, b0 = 0.f, b1v = 0.f, c0 = 0.f, c1 = 0.f, d0 = 0.f, d1 = 0.f;
    {
        unsigned int r = *(const unsigned int*)&h2s[(size_t)n * 128 + lane * 2];
        cvt2(r, a0, a1);
    }
    int beg = offs[n];
    int end = beg + cnt[n];
    int j = beg;
    for (; j + 3 < end; j += 4) {
        int s0 = csr[j], s1 = csr[j+1], s2 = csr[j+2], s3 = csr[j+3];
        unsigned int r0 = *(const unsigned int*)&h2s[(size_t)s0 * 128 + lane * 2];
        unsigned int r1 = *(const unsigned int*)&h2s[(size_t)s1 * 128 + lane * 2];
        unsigned int r2 = *(const unsigned int*)&h2s[(size_t)s2 * 128 + lane * 2];
        unsigned int r3 = *(const unsigned int*)&h2s[(size_t)s3 * 128 + lane * 2];
        float v0, v1;
        cvt2(r0, v0, v1); a0 += v0; a1 += v1;
        cvt2(r1, v0, v1); b0 += v0; b1v += v1;
        cvt2(r2, v0, v1); c0 += v0; c1 += v1;
        cvt2(r3, v0, v1); d0 += v0; d1 += v1;
    }
    for (; j < end; ++j) {
        int s0 = csr[j];
        unsigned int r0 = *(const unsigned int*)&h2s[(size_t)s0 * 128 + lane * 2];
        float v0, v1;
        cvt2(r0, v0, v1); a0 += v0; a1 += v1;
    }
    float dv = dinv[n];
    float2 bv = *(const float2*)&b2[lane * 2];
    float x0 = fmaf((a0 + b0) + (c0 + d0), dv, bv.x);
    float x1 = fmaf((a1 + b1v) + (c1 + d1), dv, bv.y);
    float s = x0 + x1;
    float q = x0*x0 + x1*x1;
    #pragma unroll
    for (int off = 32; off > 0; off >>= 1) {
        s += __shfl_xor(s, off);
        q += __shfl_xor(q, off);
    }
    float mu = s * (1.0f / 128.0f);
    float var = fmaxf(q * (1.0f / 128.0f) - mu * mu, 0.0f);
    float rstd = rsqrtf(var + 1e-5f);
    float2 gv = *(const float2*)&g2[lane * 2];
    float2 ev = *(const float2*)&be2[lane * 2];
    float o0 = fmaf((x0 - mu) * rstd, gv.x, ev.x);
    float o1 = fmaf((x1 - mu) * rstd, gv.y, ev.y);
    if (flag[0]) {
        *(float2*)&((float*)out)[(size_t)n * 128 + lane * 2] = make_float2(o0, o1);
    } else {
        unsigned int packed = (unsigned int)f2bf(o0) | ((unsigned int)f2bf(o1) << 16);
        *(unsigned int*)&((unsigned short*)out)[(size_t)n * 128 + lane * 2] = packed;
    }
}

extern "C" void kernel_launch(void* const* d_in, const int* in_sizes, int n_in,
                              void* d_out, int out_size, void* d_ws, size_t ws_size,
                              hipStream_t stream) {
    const int N = in_sizes[0];
    const int E = in_sizes[1] / 2;
    const int NB = (N + 255) / 256;

    const int* x_ids = (const int*)d_in[0];
    const int* src = (const int*)d_in[1];
    const int* dst = src + E;
    const void* embed = d_in[2];
    const void* W1 = d_in[3];
    const void* b1 = d_in[4];
    const void* g1 = d_in[5];
    const void* be1 = d_in[6];
    const void* W2 = d_in[7];
    const void* b2 = d_in[8];
    const void* g2 = d_in[9];
    const void* be2 = d_in[10];

    char* w = (char*)d_ws;
    auto take = [&](size_t bytes) { char* p = w; w += (bytes + 255) & ~(size_t)255; return p; };
    int* flag             = (int*)take(4);
    unsigned short* W1P   = (unsigned short*)take(65536);
    unsigned short* W2P   = (unsigned short*)take(65536);
    float* b1F  = (float*)take(1024);
    float* g1F  = (float*)take(1024);
    float* be1F = (float*)take(1024);
    float* b2F  = (float*)take(512);
    float* g2F  = (float*)take(512);
    float* be2F = (float*)take(512);
    int* bsum   = (int*)take(1024);
    int* boff   = (int*)take(1024);
    int* cnt    = (int*)take((size_t)N * 4);
    int* offs   = (int*)take((size_t)N * 4);
    int* cur    = (int*)take((size_t)N * 4);
    unsigned short* csr = (unsigned short*)take((size_t)E * 2);
    float* dinv = (float*)take(((size_t)N + 64) * 4);
    unsigned short* xs    = (unsigned short*)take((size_t)N * 128 * 2);
    unsigned short* agg1s = (unsigned short*)take((size_t)N * 128 * 2);
    unsigned short* x1    = (unsigned short*)take((size_t)N * 256 * 2);
    unsigned short* h2s   = agg1s;   // reuse after gemm_ln1 consumed agg1s

    zero_flag_k<<<1, 64, 0, stream>>>(flag);
    detect_k   <<<16, 256, 0, stream>>>((const unsigned int*)embed, flag);

    pack_w1_k<<<16, 256, 0, stream>>>(W1, flag, W1P);
    pack_w2_k<<<16, 256, 0, stream>>>(W2, flag, W2P);
    pack_params_k<<<1, 256, 0, stream>>>(b1, g1, be1, b2, g2, be2, flag,
                                         b1F, g1F, be1F, b2F, g2F, be2F);

    // CSR build
    zero_k    <<<NB, 256, 0, stream>>>(cnt, N);
    hist_k    <<<(E + 255) / 256, 256, 0, stream>>>(dst, cnt, E);
    blocksum_k<<<NB, 256, 0, stream>>>(cnt, bsum, N);
    scan1_k   <<<1, 256, 0, stream>>>(bsum, boff, NB);
    scan2_k   <<<NB, 256, 0, stream>>>(cnt, boff, offs, cur, dinv, N);
    fill_k    <<<(E + 255) / 256, 256, 0, stream>>>(src, dst, cur, csr, E);

    // layer 1: scale -> aggregate (128 feats) -> GEMM+bias+ReLU+LN fused
    xs_k      <<<(N * 16 + 255) / 256, 256, 0, stream>>>(x_ids, embed, dinv, flag, xs, N);
    agg1_k    <<<(N + 3) / 4, 256, 0, stream>>>(xs, offs, cnt, csr, agg1s, N);
    gemm_ln1_k<<<(N + 63) / 64, 256, 0, stream>>>(agg1s, W1P, dinv, b1F, g1F, be1F, x1, N);

    // layer 2: GEMM -> aggregate + LN (final store)
    gemm2_k   <<<(N + 63) / 64, 256, 0, stream>>>(x1, W2P, dinv, h2s, N);
    agg_ln2_k <<<(N + 3) / 4, 256, 0, stream>>>(h2s, offs, cnt, csr, dinv, b2F, g2F, be2F, flag, d_out, N);
}

// Round 7
// 315.284 us; speedup vs baseline: 13.7306x; 1.0007x over previous
//
#include <hip/hip_runtime.h>
#include <hip/hip_bf16.h>
#include <cstdint>
#include <cstddef>

typedef short bf16x8 __attribute__((ext_vector_type(8)));   // 8 bf16 (4 VGPRs)
typedef float f32x4 __attribute__((ext_vector_type(4)));    // MFMA C/D

__device__ __forceinline__ void cvt2(unsigned int u, float& lo, float& hi) {
    union { unsigned int i; float f; } a, b;
    a.i = u << 16;
    b.i = u & 0xffff0000u;
    lo = a.f; hi = b.f;
}
__device__ __forceinline__ float bf2f(unsigned short s) {
    union { unsigned int i; float f; } c; c.i = ((unsigned int)s) << 16;
    return c.f;
}
__device__ __forceinline__ unsigned short f2bf(float f) {
    union { float f; unsigned int i; } c; c.f = f;
    unsigned int x = c.i;
    unsigned int r = (x + 0x7fffu + ((x >> 16) & 1u)) >> 16;
    return (unsigned short)r;
}

__global__ __launch_bounds__(64) void zero_flag_k(int* __restrict__ flag) {
    if (threadIdx.x == 0) flag[0] = 0;
}

// parallel dtype detect: low-half-as-bf16 magnitude explodes iff data is fp32
__global__ __launch_bounds__(256) void detect_k(const unsigned int* __restrict__ emb,
                                                int* __restrict__ flag) {
    __shared__ unsigned int red[256];
    int t = threadIdx.x;
    unsigned int m = 0;
    int base = blockIdx.x * 4096;
    #pragma unroll
    for (int i = 0; i < 16; ++i) {
        unsigned int u = emb[base + t + 256 * i];
        unsigned int lo = (u << 16) & 0x7fffffffu;
        m = m > lo ? m : lo;
    }
    red[t] = m; __syncthreads();
    for (int s = 128; s > 0; s >>= 1) {
        if (t < s) red[t] = red[t] > red[t + s] ? red[t] : red[t + s];
        __syncthreads();
    }
    if (t == 0 && red[0] > 0x4B000000u) atomicOr(flag, 1);   // > 2^23 => fp32
}

__device__ __forceinline__ unsigned short in_bf16(const void* p, size_t i, int f) {
    if (f) return f2bf(((const float*)p)[i]);
    return ((const unsigned short*)p)[i];
}
__device__ __forceinline__ float in_f32(const void* p, size_t i, int f) {
    if (f) return ((const float*)p)[i];
    return bf2f(((const unsigned short*)p)[i]);
}

// pack W1 [128][256] into per-MFMA-fragment layout: frag (jt 0..15, kk 0..3)
__global__ __launch_bounds__(256) void pack_w1_k(const void* __restrict__ W1,
                                                 const int* __restrict__ flag,
                                                 unsigned short* __restrict__ W1P) {
    int tid = blockIdx.x * 256 + threadIdx.x;       // 0..4095
    if (tid >= 16 * 4 * 64) return;
    int lane = tid & 63, kk = (tid >> 6) & 3, jt = tid >> 8;
    int col = jt * 16 + (lane & 15);
    int k0 = kk * 32 + (lane >> 4) * 8;
    int f = flag[0];
    unsigned short v[8];
    #pragma unroll
    for (int j = 0; j < 8; ++j) v[j] = in_bf16(W1, (size_t)(k0 + j) * 256 + col, f);
    #pragma unroll
    for (int j = 0; j < 8; ++j) W1P[(size_t)tid * 8 + j] = v[j];
}

// pack W2 [256][128]: frag (jt 0..7, kk 0..7)
__global__ __launch_bounds__(256) void pack_w2_k(const void* __restrict__ W2,
                                                 const int* __restrict__ flag,
                                                 unsigned short* __restrict__ W2P) {
    int tid = blockIdx.x * 256 + threadIdx.x;       // 0..4095
    if (tid >= 8 * 8 * 64) return;
    int lane = tid & 63, kk = (tid >> 6) & 7, jt = tid >> 9;
    int col = jt * 16 + (lane & 15);
    int k0 = kk * 32 + (lane >> 4) * 8;
    int f = flag[0];
    unsigned short v[8];
    #pragma unroll
    for (int j = 0; j < 8; ++j) v[j] = in_bf16(W2, (size_t)(k0 + j) * 128 + col, f);
    #pragma unroll
    for (int j = 0; j < 8; ++j) W2P[(size_t)tid * 8 + j] = v[j];
}

__global__ __launch_bounds__(256) void pack_params_k(
    const void* b1, const void* g1, const void* be1,
    const void* b2, const void* g2, const void* be2,
    const int* __restrict__ flag,
    float* b1F, float* g1F, float* be1F, float* b2F, float* g2F, float* be2F) {
    int t = threadIdx.x;
    int f = flag[0];
    b1F[t]  = in_f32(b1, t, f);
    g1F[t]  = in_f32(g1, t, f);
    be1F[t] = in_f32(be1, t, f);
    if (t < 128) {
        b2F[t]  = in_f32(b2, t, f);
        g2F[t]  = in_f32(g2, t, f);
        be2F[t] = in_f32(be2, t, f);
    }
}

// ---------------- CSR build ----------------
__global__ __launch_bounds__(256) void zero_k(int* __restrict__ p, int n) {
    int i = blockIdx.x * 256 + threadIdx.x;
    if (i < n) p[i] = 0;
}
// nt-load the dst stream: no L2 retention needed for it; keep cnt lines resident
__global__ __launch_bounds__(256) void hist_k(const int* __restrict__ dst,
                                              int* __restrict__ cnt, int E) {
    int e = blockIdx.x * 256 + threadIdx.x;
    if (e < E) {
        int d = __builtin_nontemporal_load(&dst[e]);
        atomicAdd(&cnt[d], 1);
    }
}
__global__ __launch_bounds__(256) void blocksum_k(const int* __restrict__ cnt,
                                                  int* __restrict__ bsum, int N) {
    __shared__ int red[256];
    int t = threadIdx.x;
    int i = blockIdx.x * 256 + t;
    red[t] = (i < N) ? cnt[i] : 0;
    __syncthreads();
    for (int s = 128; s > 0; s >>= 1) {
        if (t < s) red[t] += red[t + s];
        __syncthreads();
    }
    if (t == 0) bsum[blockIdx.x] = red[0];
}
__global__ __launch_bounds__(256) void scan1_k(const int* __restrict__ bsum,
                                               int* __restrict__ boff, int NB) {
    __shared__ int sh[256];
    int t = threadIdx.x;
    int v = (t < NB) ? bsum[t] : 0;
    sh[t] = v; __syncthreads();
    for (int o = 1; o < 256; o <<= 1) {
        int u = (t >= o) ? sh[t - o] : 0;
        __syncthreads();
        sh[t] += u;
        __syncthreads();
    }
    if (t < NB) boff[t] = sh[t] - v;
}
// per-chunk exclusive scan + chunk offset -> offs/cur; also dinv = rsqrt(cnt+1)
__global__ __launch_bounds__(256) void scan2_k(const int* __restrict__ cnt,
                                               const int* __restrict__ boff,
                                               int* __restrict__ offs,
                                               int* __restrict__ cur,
                                               float* __restrict__ dinv, int N) {
    __shared__ int sh[256];
    int t = threadIdx.x;
    int i = blockIdx.x * 256 + t;
    int v = (i < N) ? cnt[i] : 0;
    sh[t] = v; __syncthreads();
    for (int o = 1; o < 256; o <<= 1) {
        int u = (t >= o) ? sh[t - o] : 0;
        __syncthreads();
        sh[t] += u;
        __syncthreads();
    }
    if (i < N) {
        int excl = sh[t] - v + boff[blockIdx.x];
        offs[i] = excl;
        cur[i] = excl;
        dinv[i] = rsqrtf((float)(v + 1));
    }
}
// csr entries as ushort (node ids < 65536); nt-load the src/dst streams so the
// scattered 2B csr writes keep their dirty L2 lines resident until kernel end
__global__ __launch_bounds__(256) void fill_k(const int* __restrict__ src,
                                              const int* __restrict__ dst,
                                              int* __restrict__ cur,
                                              unsigned short* __restrict__ csr, int E) {
    int e = blockIdx.x * 256 + threadIdx.x;
    if (e >= E) return;
    int d = __builtin_nontemporal_load(&dst[e]);
    int s = __builtin_nontemporal_load(&src[e]);
    int slot = atomicAdd(&cur[d], 1);
    csr[slot] = (unsigned short)s;
}

// xs[n] = bf16(dinv[n] * embed[x_ids[n]]), 16 threads/node x 8 feats
__global__ __launch_bounds__(256) void xs_k(
    const int* __restrict__ x_ids, const void* __restrict__ embed,
    const float* __restrict__ dinv, const int* __restrict__ flag,
    unsigned short* __restrict__ xs, int N)
{
    int tid = blockIdx.x * 256 + threadIdx.x;
    int n = tid >> 4;
    int c = tid & 15;
    if (n >= N) return;
    int id = x_ids[n];
    float dv = dinv[n];
    int f = flag[0];
    float v[8];
    if (f) {
        const float* er = (const float*)embed + (size_t)id * 128 + c * 8;
        float4 a = *(const float4*)er;
        float4 b = *(const float4*)(er + 4);
        v[0]=a.x; v[1]=a.y; v[2]=a.z; v[3]=a.w;
        v[4]=b.x; v[5]=b.y; v[6]=b.z; v[7]=b.w;
    } else {
        uint4 u = *(const uint4*)((const unsigned short*)embed + (size_t)id * 128 + c * 8);
        cvt2(u.x, v[0], v[1]); cvt2(u.y, v[2], v[3]);
        cvt2(u.z, v[4], v[5]); cvt2(u.w, v[6], v[7]);
    }
    union { unsigned short s[8]; uint4 u; } o;
    #pragma unroll
    for (int j = 0; j < 8; ++j) o.s[j] = f2bf(v[j] * dv);
    *(uint4*)&xs[(size_t)n * 128 + c * 8] = o.u;
}

// agg1s[d] = xs[d] + sum_{s in N(d)} xs[s]   (wave/node, 2 feats/lane, 8-way MLP)
__global__ __launch_bounds__(256) void agg1_k(
    const unsigned short* __restrict__ xs, const int* __restrict__ offs,
    const int* __restrict__ cnt, const unsigned short* __restrict__ csr,
    unsigned short* __restrict__ agg1s, int N)
{
    int lane = threadIdx.x & 63;
    int n = blockIdx.x * 4 + (threadIdx.x >> 6);
    if (n >= N) return;

    float ax[8], ay[8];
    #pragma unroll
    for (int i = 0; i < 8; ++i) { ax[i] = 0.f; ay[i] = 0.f; }
    {
        unsigned int r = *(const unsigned int*)&xs[(size_t)n * 128 + lane * 2];
        cvt2(r, ax[0], ay[0]);
    }
    int beg = offs[n];
    int end = beg + cnt[n];
    int j = beg;
    for (; j + 7 < end; j += 8) {
        unsigned int rr[8];
        #pragma unroll
        for (int i = 0; i < 8; ++i) {
            int s = __builtin_nontemporal_load(&csr[j + i]);
            rr[i] = *(const unsigned int*)&xs[(size_t)s * 128 + lane * 2];
        }
        #pragma unroll
        for (int i = 0; i < 8; ++i) {
            float v0, v1; cvt2(rr[i], v0, v1);
            ax[i] += v0; ay[i] += v1;
        }
    }
    for (; j + 1 < end; j += 2) {
        int s0 = __builtin_nontemporal_load(&csr[j]);
        int s1 = __builtin_nontemporal_load(&csr[j + 1]);
        unsigned int r0 = *(const unsigned int*)&xs[(size_t)s0 * 128 + lane * 2];
        unsigned int r1 = *(const unsigned int*)&xs[(size_t)s1 * 128 + lane * 2];
        float v0, v1; cvt2(r0, v0, v1); ax[0] += v0; ay[0] += v1;
        cvt2(r1, v0, v1); ax[1] += v0; ay[1] += v1;
    }
    if (j < end) {
        int s0 = __builtin_nontemporal_load(&csr[j]);
        unsigned int r0 = *(const unsigned int*)&xs[(size_t)s0 * 128 + lane * 2];
        float v0, v1; cvt2(r0, v0, v1); ax[0] += v0; ay[0] += v1;
    }
    float o0 = ((ax[0]+ax[1])+(ax[2]+ax[3])) + ((ax[4]+ax[5])+(ax[6]+ax[7]));
    float o1 = ((ay[0]+ay[1])+(ay[2]+ay[3])) + ((ay[4]+ay[5])+(ay[6]+ay[7]));
    unsigned int pk = (unsigned int)f2bf(o0) | ((unsigned int)f2bf(o1) << 16);
    *(unsigned int*)&agg1s[(size_t)n * 128 + lane * 2] = pk;
}

// GEMM1 + bias + ReLU + LN fused: x1[n] = LN(relu(dinv[n]*(agg1s[n]@W1) + b1))
__global__ __launch_bounds__(256) void gemm_ln1_k(
    const unsigned short* __restrict__ agg1s, const unsigned short* __restrict__ W1P,
    const float* __restrict__ dinv, const float* __restrict__ b1,
    const float* __restrict__ g1, const float* __restrict__ be1,
    unsigned short* __restrict__ x1, int N)
{
    const int t = threadIdx.x;
    const int w = t >> 6;
    const int lane = t & 63;
    const int m = lane & 15;
    const int quad = lane >> 4;
    const int nb = blockIdx.x * 64;

    int node_a = nb + w * 16 + m;
    int idn = node_a < N ? node_a : N - 1;
    const unsigned short* er = agg1s + (size_t)idn * 128 + quad * 8;
    bf16x8 a[4];
    #pragma unroll
    for (int kk = 0; kk < 4; ++kk)
        a[kk] = *(const bf16x8*)(er + kk * 32);

    f32x4 acc[16];
    #pragma unroll
    for (int jt = 0; jt < 16; ++jt) acc[jt] = (f32x4){0.f, 0.f, 0.f, 0.f};

    #pragma unroll
    for (int kk = 0; kk < 4; ++kk) {
        #pragma unroll
        for (int jt = 0; jt < 16; ++jt) {
            bf16x8 b = *(const bf16x8*)(W1P + ((size_t)(jt * 4 + kk) * 64 + lane) * 8);
            acc[jt] = __builtin_amdgcn_mfma_f32_16x16x32_bf16(a[kk], b, acc[jt], 0, 0, 0);
        }
    }

    float bcol[16], gcol[16], ecol[16];
    #pragma unroll
    for (int jt = 0; jt < 16; ++jt) {
        bcol[jt] = b1[jt * 16 + m];
        gcol[jt] = g1[jt * 16 + m];
        ecol[jt] = be1[jt * 16 + m];
    }
    int base = nb + w * 16 + quad * 4;
    float4 dv4 = *(const float4*)&dinv[base < N ? base : 0];
    float dvr[4] = {dv4.x, dv4.y, dv4.z, dv4.w};

    #pragma unroll
    for (int reg = 0; reg < 4; ++reg) {
        int row = base + reg;
        float v[16];
        float s = 0.f, q = 0.f;
        #pragma unroll
        for (int jt = 0; jt < 16; ++jt) {
            float x = fmaxf(fmaf(acc[jt][reg], dvr[reg], bcol[jt]), 0.0f);
            v[jt] = x;
            s += x; q += x * x;
        }
        #pragma unroll
        for (int off = 1; off < 16; off <<= 1) {
            s += __shfl_xor(s, off);
            q += __shfl_xor(q, off);
        }
        float mu = s * (1.0f / 256.0f);
        float var = fmaxf(q * (1.0f / 256.0f) - mu * mu, 0.0f);
        float rstd = rsqrtf(var + 1e-5f);
        if (row < N) {
            unsigned short* xp = x1 + (size_t)row * 256 + m;
            #pragma unroll
            for (int jt = 0; jt < 16; ++jt)
                xp[jt * 16] = f2bf(fmaf((v[jt] - mu) * rstd, gcol[jt], ecol[jt]));
        }
    }
}

// GEMM2 (MFMA): h2s[n][j] = bf16( dinv[n] * sum_k x1[n][k] * W2[k][j] )
__global__ __launch_bounds__(256) void gemm2_k(
    const unsigned short* __restrict__ x1, const unsigned short* __restrict__ W2P,
    const float* __restrict__ dinv, unsigned short* __restrict__ h2s, int N)
{
    const int t = threadIdx.x;
    const int w = t >> 6;
    const int lane = t & 63;
    const int m = lane & 15;
    const int quad = lane >> 4;
    const int nb = blockIdx.x * 64;

    int node_a = nb + w * 16 + m;
    int idn = node_a < N ? node_a : N - 1;

    const unsigned short* er = x1 + (size_t)idn * 256 + quad * 8;
    bf16x8 a[8];
    #pragma unroll
    for (int kk = 0; kk < 8; ++kk)
        a[kk] = *(const bf16x8*)(er + kk * 32);

    f32x4 acc[8];
    #pragma unroll
    for (int jt = 0; jt < 8; ++jt) acc[jt] = (f32x4){0.f, 0.f, 0.f, 0.f};

    #pragma unroll
    for (int kk = 0; kk < 8; ++kk) {
        #pragma unroll
        for (int jt = 0; jt < 8; ++jt) {
            bf16x8 b = *(const bf16x8*)(W2P + ((size_t)(jt * 8 + kk) * 64 + lane) * 8);
            acc[jt] = __builtin_amdgcn_mfma_f32_16x16x32_bf16(a[kk], b, acc[jt], 0, 0, 0);
        }
    }

    int base = nb + w * 16 + quad * 4;
    float4 dv4 = *(const float4*)&dinv[base < N ? base : 0];
    float dvr[4] = {dv4.x, dv4.y, dv4.z, dv4.w};
    #pragma unroll
    for (int reg = 0; reg < 4; ++reg) {
        int node_r = base + reg;
        if (node_r < N) {
            unsigned short* hp = h2s + (size_t)node_r * 128 + m;
            #pragma unroll
            for (int jt = 0; jt < 8; ++jt)
                hp[jt * 16] = f2bf(acc[jt][reg] * dvr[reg]);
        }
    }
}

// fused gather-aggregate + LN layer 2 (128 feats, wave/node, 8-way MLP), final store
__global__ __launch_bounds__(256) void agg_ln2_k(
    const unsigned short* __restrict__ h2s, const int* __restrict__ offs,
    const int* __restrict__ cnt, const unsigned short* __restrict__ csr,
    const float* __restrict__ dinv, const float* __restrict__ b2,
    const float* __restrict__ g2, const float* __restrict__ be2,
    const int* __restrict__ flag, void* __restrict__ out, int N)
{
    int lane = threadIdx.x & 63;
    int n = blockIdx.x * 4 + (threadIdx.x >> 6);
    if (n >= N) return;

    float ax[8], ay[8];
    #pragma unroll
    for (int i = 0; i < 8; ++i) { ax[i] = 0.f; ay[i] = 0.f; }
    {
        unsigned int r = *(const unsigned int*)&h2s[(size_t)n * 128 + lane * 2];
        cvt2(r, ax[0], ay[0]);
    }
    int beg = offs[n];
    int end = beg + cnt[n];
    int j = beg;
    for (; j + 7 < end; j += 8) {
        unsigned int rr[8];
        #pragma unroll
        for (int i = 0; i < 8; ++i) {
            int s = __builtin_nontemporal_load(&csr[j + i]);
            rr[i] = *(const unsigned int*)&h2s[(size_t)s * 128 + lane * 2];
        }
        #pragma unroll
        for (int i = 0; i < 8; ++i) {
            float v0, v1; cvt2(rr[i], v0, v1);
            ax[i] += v0; ay[i] += v1;
        }
    }
    for (; j + 1 < end; j += 2) {
        int s0 = __builtin_nontemporal_load(&csr[j]);
        int s1 = __builtin_nontemporal_load(&csr[j + 1]);
        unsigned int r0 = *(const unsigned int*)&h2s[(size_t)s0 * 128 + lane * 2];
        unsigned int r1 = *(const unsigned int*)&h2s[(size_t)s1 * 128 + lane * 2];
        float v0, v1; cvt2(r0, v0, v1); ax[0] += v0; ay[0] += v1;
        cvt2(r1, v0, v1); ax[1] += v0; ay[1] += v1;
    }
    if (j < end) {
        int s0 = __builtin_nontemporal_load(&csr[j]);
        unsigned int r0 = *(const unsigned int*)&h2s[(size_t)s0 * 128 + lane * 2];
        float v0, v1; cvt2(r0, v0, v1); ax[0] += v0; ay[0] += v1;
    }
    float sum0 = ((ax[0]+ax[1])+(ax[2]+ax[3])) + ((ax[4]+ax[5])+(ax[6]+ax[7]));
    float sum1 = ((ay[0]+ay[1])+(ay[2]+ay[3])) + ((ay[4]+ay[5])+(ay[6]+ay[7]));
    float dv = dinv[n];
    float2 bv = *(const float2*)&b2[lane * 2];
    float x0 = fmaf(sum0, dv, bv.x);
    float x1 = fmaf(sum1, dv, bv.y);
    float s = x0 + x1;
    float q = x0*x0 + x1*x1;
    #pragma unroll
    for (int off = 32; off > 0; off >>= 1) {
        s += __shfl_xor(s, off);
        q += __shfl_xor(q, off);
    }
    float mu = s * (1.0f / 128.0f);
    float var = fmaxf(q * (1.0f / 128.0f) - mu * mu, 0.0f);
    float rstd = rsqrtf(var + 1e-5f);
    float2 gv = *(const float2*)&g2[lane * 2];
    float2 ev = *(const float2*)&be2[lane * 2];
    float o0 = fmaf((x0 - mu) * rstd, gv.x, ev.x);
    float o1 = fmaf((x1 - mu) * rstd, gv.y, ev.y);
    if (flag[0]) {
        *(float2*)&((float*)out)[(size_t)n * 128 + lane * 2] = make_float2(o0, o1);
    } else {
        unsigned int packed = (unsigned int)f2bf(o0) | ((unsigned int)f2bf(o1) << 16);
        *(unsigned int*)&((unsigned short*)out)[(size_t)n * 128 + lane * 2] = packed;
    }
}

extern "C" void kernel_launch(void* const* d_in, const int* in_sizes, int n_in,
                              void* d_out, int out_size, void* d_ws, size_t ws_size,
                              hipStream_t stream) {
    const int N = in_sizes[0];
    const int E = in_sizes[1] / 2;
    const int NB = (N + 255) / 256;

    const int* x_ids = (const int*)d_in[0];
    const int* src = (const int*)d_in[1];
    const int* dst = src + E;
    const void* embed = d_in[2];
    const void* W1 = d_in[3];
    const void* b1 = d_in[4];
    const void* g1 = d_in[5];
    const void* be1 = d_in[6];
    const void* W2 = d_in[7];
    const void* b2 = d_in[8];
    const void* g2 = d_in[9];
    const void* be2 = d_in[10];

    char* w = (char*)d_ws;
    auto take = [&](size_t bytes) { char* p = w; w += (bytes + 255) & ~(size_t)255; return p; };
    int* flag             = (int*)take(4);
    unsigned short* W1P   = (unsigned short*)take(65536);
    unsigned short* W2P   = (unsigned short*)take(65536);
    float* b1F  = (float*)take(1024);
    float* g1F  = (float*)take(1024);
    float* be1F = (float*)take(1024);
    float* b2F  = (float*)take(512);
    float* g2F  = (float*)take(512);
    float* be2F = (float*)take(512);
    int* bsum   = (int*)take(1024);
    int* boff   = (int*)take(1024);
    int* cnt    = (int*)take((size_t)N * 4);
    int* offs   = (int*)take((size_t)N * 4);
    int* cur    = (int*)take((size_t)N * 4);
    unsigned short* csr = (unsigned short*)take((size_t)E * 2);
    float* dinv = (float*)take(((size_t)N + 64) * 4);
    unsigned short* xs    = (unsigned short*)take((size_t)N * 128 * 2);
    unsigned short* agg1s = (unsigned short*)take((size_t)N * 128 * 2);
    unsigned short* x1    = (unsigned short*)take((size_t)N * 256 * 2);
    unsigned short* h2s   = agg1s;   // reuse after gemm_ln1 consumed agg1s

    zero_flag_k<<<1, 64, 0, stream>>>(flag);
    detect_k   <<<16, 256, 0, stream>>>((const unsigned int*)embed, flag);

    pack_w1_k<<<16, 256, 0, stream>>>(W1, flag, W1P);
    pack_w2_k<<<16, 256, 0, stream>>>(W2, flag, W2P);
    pack_params_k<<<1, 256, 0, stream>>>(b1, g1, be1, b2, g2, be2, flag,
                                         b1F, g1F, be1F, b2F, g2F, be2F);

    // CSR build
    zero_k    <<<NB, 256, 0, stream>>>(cnt, N);
    hist_k    <<<(E + 255) / 256, 256, 0, stream>>>(dst, cnt, E);
    blocksum_k<<<NB, 256, 0, stream>>>(cnt, bsum, N);
    scan1_k   <<<1, 256, 0, stream>>>(bsum, boff, NB);
    scan2_k   <<<NB, 256, 0, stream>>>(cnt, boff, offs, cur, dinv, N);
    fill_k    <<<(E + 255) / 256, 256, 0, stream>>>(src, dst, cur, csr, E);

    // layer 1: scale -> aggregate (128 feats) -> GEMM+bias+ReLU+LN fused
    xs_k      <<<(N * 16 + 255) / 256, 256, 0, stream>>>(x_ids, embed, dinv, flag, xs, N);
    agg1_k    <<<(N + 3) / 4, 256, 0, stream>>>(xs, offs, cnt, csr, agg1s, N);
    gemm_ln1_k<<<(N + 63) / 64, 256, 0, stream>>>(agg1s, W1P, dinv, b1F, g1F, be1F, x1, N);

    // layer 2: GEMM -> aggregate + LN (final store)
    gemm2_k   <<<(N + 63) / 64, 256, 0, stream>>>(x1, W2P, dinv, h2s, N);
    agg_ln2_k <<<(N + 3) / 4, 256, 0, stream>>>(h2s, offs, cnt, csr, dinv, b2F, g2F, be2F, flag, d_out, N);
}

// Round 8
// 292.649 us; speedup vs baseline: 14.7926x; 1.0773x over previous
//
#include <hip/hip_runtime.h>
#include <hip/hip_bf16.h>
#include <cstdint>
#include <cstddef>

typedef short bf16x8 __attribute__((ext_vector_type(8)));   // 8 bf16 (4 VGPRs)
typedef float f32x4 __attribute__((ext_vector_type(4)));    // MFMA C/D

__device__ __forceinline__ void cvt2(unsigned int u, float& lo, float& hi) {
    union { unsigned int i; float f; } a, b;
    a.i = u << 16;
    b.i = u & 0xffff0000u;
    lo = a.f; hi = b.f;
}
__device__ __forceinline__ float bf2f(unsigned short s) {
    union { unsigned int i; float f; } c; c.i = ((unsigned int)s) << 16;
    return c.f;
}
__device__ __forceinline__ unsigned short f2bf(float f) {
    union { float f; unsigned int i; } c; c.f = f;
    unsigned int x = c.i;
    unsigned int r = (x + 0x7fffu + ((x >> 16) & 1u)) >> 16;
    return (unsigned short)r;
}

__global__ __launch_bounds__(64) void zero_flag_k(int* __restrict__ flag) {
    if (threadIdx.x == 0) flag[0] = 0;
}

// merged: blocks 0..15 detect dtype; blocks 16.. zero cnt
__global__ __launch_bounds__(256) void detect_zero_k(const unsigned int* __restrict__ emb,
                                                     int* __restrict__ flag,
                                                     int* __restrict__ cnt, int N) {
    if (blockIdx.x < 16) {
        __shared__ unsigned int red[256];
        int t = threadIdx.x;
        unsigned int m = 0;
        int base = blockIdx.x * 4096;
        #pragma unroll
        for (int i = 0; i < 16; ++i) {
            unsigned int u = emb[base + t + 256 * i];
            unsigned int lo = (u << 16) & 0x7fffffffu;
            m = m > lo ? m : lo;
        }
        red[t] = m; __syncthreads();
        for (int s = 128; s > 0; s >>= 1) {
            if (t < s) red[t] = red[t] > red[t + s] ? red[t] : red[t + s];
            __syncthreads();
        }
        if (t == 0 && red[0] > 0x4B000000u) atomicOr(flag, 1);   // > 2^23 => fp32
    } else {
        int i = (blockIdx.x - 16) * 256 + threadIdx.x;
        if (i < N) cnt[i] = 0;
    }
}

__device__ __forceinline__ unsigned short in_bf16(const void* p, size_t i, int f) {
    if (f) return f2bf(((const float*)p)[i]);
    return ((const unsigned short*)p)[i];
}
__device__ __forceinline__ float in_f32(const void* p, size_t i, int f) {
    if (f) return ((const float*)p)[i];
    return bf2f(((const unsigned short*)p)[i]);
}

// merged pack: blocks 0..15 W1 frags, 16..31 W2 frags, 32 LN/bias params
__global__ __launch_bounds__(256) void pack_k(
    const void* __restrict__ W1, const void* __restrict__ W2,
    const void* b1, const void* g1, const void* be1,
    const void* b2, const void* g2, const void* be2,
    const int* __restrict__ flag,
    unsigned short* __restrict__ W1P, unsigned short* __restrict__ W2P,
    float* b1F, float* g1F, float* be1F, float* b2F, float* g2F, float* be2F) {
    int f = flag[0];
    if (blockIdx.x < 16) {
        int tid = blockIdx.x * 256 + threadIdx.x;       // 0..4095
        int lane = tid & 63, kk = (tid >> 6) & 3, jt = tid >> 8;
        int col = jt * 16 + (lane & 15);
        int k0 = kk * 32 + (lane >> 4) * 8;
        unsigned short v[8];
        #pragma unroll
        for (int j = 0; j < 8; ++j) v[j] = in_bf16(W1, (size_t)(k0 + j) * 256 + col, f);
        #pragma unroll
        for (int j = 0; j < 8; ++j) W1P[(size_t)tid * 8 + j] = v[j];
    } else if (blockIdx.x < 32) {
        int tid = (blockIdx.x - 16) * 256 + threadIdx.x; // 0..4095
        int lane = tid & 63, kk = (tid >> 6) & 7, jt = tid >> 9;
        int col = jt * 16 + (lane & 15);
        int k0 = kk * 32 + (lane >> 4) * 8;
        unsigned short v[8];
        #pragma unroll
        for (int j = 0; j < 8; ++j) v[j] = in_bf16(W2, (size_t)(k0 + j) * 128 + col, f);
        #pragma unroll
        for (int j = 0; j < 8; ++j) W2P[(size_t)tid * 8 + j] = v[j];
    } else {
        int t = threadIdx.x;
        b1F[t]  = in_f32(b1, t, f);
        g1F[t]  = in_f32(g1, t, f);
        be1F[t] = in_f32(be1, t, f);
        if (t < 128) {
            b2F[t]  = in_f32(b2, t, f);
            g2F[t]  = in_f32(g2, t, f);
            be2F[t] = in_f32(be2, t, f);
        }
    }
}

// ---------------- CSR build ----------------
__global__ __launch_bounds__(256) void hist_k(const int* __restrict__ dst,
                                              int* __restrict__ cnt, int E) {
    int e = blockIdx.x * 256 + threadIdx.x;
    if (e < E) {
        int d = __builtin_nontemporal_load(&dst[e]);
        atomicAdd(&cnt[d], 1);
    }
}
__global__ __launch_bounds__(256) void blocksum_k(const int* __restrict__ cnt,
                                                  int* __restrict__ bsum, int N) {
    __shared__ int red[256];
    int t = threadIdx.x;
    int i = blockIdx.x * 256 + t;
    red[t] = (i < N) ? cnt[i] : 0;
    __syncthreads();
    for (int s = 128; s > 0; s >>= 1) {
        if (t < s) red[t] += red[t + s];
        __syncthreads();
    }
    if (t == 0) bsum[blockIdx.x] = red[0];
}
__global__ __launch_bounds__(256) void scan1_k(const int* __restrict__ bsum,
                                               int* __restrict__ boff, int NB) {
    __shared__ int sh[256];
    int t = threadIdx.x;
    int v = (t < NB) ? bsum[t] : 0;
    sh[t] = v; __syncthreads();
    for (int o = 1; o < 256; o <<= 1) {
        int u = (t >= o) ? sh[t - o] : 0;
        __syncthreads();
        sh[t] += u;
        __syncthreads();
    }
    if (t < NB) boff[t] = sh[t] - v;
}
// per-chunk exclusive scan + chunk offset -> offs/cur; also dinv = rsqrt(cnt+1)
__global__ __launch_bounds__(256) void scan2_k(const int* __restrict__ cnt,
                                               const int* __restrict__ boff,
                                               int* __restrict__ offs,
                                               int* __restrict__ cur,
                                               float* __restrict__ dinv, int N) {
    __shared__ int sh[256];
    int t = threadIdx.x;
    int i = blockIdx.x * 256 + t;
    int v = (i < N) ? cnt[i] : 0;
    sh[t] = v; __syncthreads();
    for (int o = 1; o < 256; o <<= 1) {
        int u = (t >= o) ? sh[t - o] : 0;
        __syncthreads();
        sh[t] += u;
        __syncthreads();
    }
    if (i < N) {
        int excl = sh[t] - v + boff[blockIdx.x];
        offs[i] = excl;
        cur[i] = excl;
        dinv[i] = rsqrtf((float)(v + 1));
    }
}
__global__ __launch_bounds__(256) void fill_k(const int* __restrict__ src,
                                              const int* __restrict__ dst,
                                              int* __restrict__ cur,
                                              unsigned short* __restrict__ csr, int E) {
    int e = blockIdx.x * 256 + threadIdx.x;
    if (e >= E) return;
    int d = __builtin_nontemporal_load(&dst[e]);
    int s = __builtin_nontemporal_load(&src[e]);
    int slot = atomicAdd(&cur[d], 1);
    csr[slot] = (unsigned short)s;
}

// xs[n] = bf16(dinv[n] * embed[x_ids[n]]), 16 threads/node x 8 feats
__global__ __launch_bounds__(256) void xs_k(
    const int* __restrict__ x_ids, const void* __restrict__ embed,
    const float* __restrict__ dinv, const int* __restrict__ flag,
    unsigned short* __restrict__ xs, int N)
{
    int tid = blockIdx.x * 256 + threadIdx.x;
    int n = tid >> 4;
    int c = tid & 15;
    if (n >= N) return;
    int id = x_ids[n];
    float dv = dinv[n];
    int f = flag[0];
    float v[8];
    if (f) {
        const float* er = (const float*)embed + (size_t)id * 128 + c * 8;
        float4 a = *(const float4*)er;
        float4 b = *(const float4*)(er + 4);
        v[0]=a.x; v[1]=a.y; v[2]=a.z; v[3]=a.w;
        v[4]=b.x; v[5]=b.y; v[6]=b.z; v[7]=b.w;
    } else {
        uint4 u = *(const uint4*)((const unsigned short*)embed + (size_t)id * 128 + c * 8);
        cvt2(u.x, v[0], v[1]); cvt2(u.y, v[2], v[3]);
        cvt2(u.z, v[4], v[5]); cvt2(u.w, v[6], v[7]);
    }
    union { unsigned short s[8]; uint4 u; } o;
    #pragma unroll
    for (int j = 0; j < 8; ++j) o.s[j] = f2bf(v[j] * dv);
    *(uint4*)&xs[(size_t)n * 128 + c * 8] = o.u;
}

#define AGG_WAVES 8192

// agg1s[d] = xs[d] + sum_{s in N(d)} xs[s]; persistent grid-stride waves
__global__ __launch_bounds__(256) void agg1_k(
    const unsigned short* __restrict__ xs, const int* __restrict__ offs,
    const int* __restrict__ cnt, const unsigned short* __restrict__ csr,
    unsigned short* __restrict__ agg1s, int N)
{
    int lane = threadIdx.x & 63;
    int wid = blockIdx.x * 4 + (threadIdx.x >> 6);

    for (int n = wid; n < N; n += AGG_WAVES) {
        float ax[8], ay[8];
        #pragma unroll
        for (int i = 0; i < 8; ++i) { ax[i] = 0.f; ay[i] = 0.f; }
        {
            unsigned int r = *(const unsigned int*)&xs[(size_t)n * 128 + lane * 2];
            cvt2(r, ax[0], ay[0]);
        }
        int beg = offs[n];
        int end = beg + cnt[n];
        int j = beg;
        for (; j + 7 < end; j += 8) {
            unsigned int rr[8];
            #pragma unroll
            for (int i = 0; i < 8; ++i) {
                int s = csr[j + i];
                rr[i] = *(const unsigned int*)&xs[(size_t)s * 128 + lane * 2];
            }
            #pragma unroll
            for (int i = 0; i < 8; ++i) {
                float v0, v1; cvt2(rr[i], v0, v1);
                ax[i] += v0; ay[i] += v1;
            }
        }
        for (; j + 1 < end; j += 2) {
            int s0 = csr[j], s1 = csr[j + 1];
            unsigned int r0 = *(const unsigned int*)&xs[(size_t)s0 * 128 + lane * 2];
            unsigned int r1 = *(const unsigned int*)&xs[(size_t)s1 * 128 + lane * 2];
            float v0, v1; cvt2(r0, v0, v1); ax[0] += v0; ay[0] += v1;
            cvt2(r1, v0, v1); ax[1] += v0; ay[1] += v1;
        }
        if (j < end) {
            int s0 = csr[j];
            unsigned int r0 = *(const unsigned int*)&xs[(size_t)s0 * 128 + lane * 2];
            float v0, v1; cvt2(r0, v0, v1); ax[0] += v0; ay[0] += v1;
        }
        float o0 = ((ax[0]+ax[1])+(ax[2]+ax[3])) + ((ax[4]+ax[5])+(ax[6]+ax[7]));
        float o1 = ((ay[0]+ay[1])+(ay[2]+ay[3])) + ((ay[4]+ay[5])+(ay[6]+ay[7]));
        unsigned int pk = (unsigned int)f2bf(o0) | ((unsigned int)f2bf(o1) << 16);
        *(unsigned int*)&agg1s[(size_t)n * 128 + lane * 2] = pk;
    }
}

// GEMM1 + bias + ReLU + LN fused: x1[n] = LN(relu(dinv[n]*(agg1s[n]@W1) + b1))
__global__ __launch_bounds__(256) void gemm_ln1_k(
    const unsigned short* __restrict__ agg1s, const unsigned short* __restrict__ W1P,
    const float* __restrict__ dinv, const float* __restrict__ b1,
    const float* __restrict__ g1, const float* __restrict__ be1,
    unsigned short* __restrict__ x1, int N)
{
    const int t = threadIdx.x;
    const int w = t >> 6;
    const int lane = t & 63;
    const int m = lane & 15;
    const int quad = lane >> 4;
    const int nb = blockIdx.x * 64;

    int node_a = nb + w * 16 + m;
    int idn = node_a < N ? node_a : N - 1;
    const unsigned short* er = agg1s + (size_t)idn * 128 + quad * 8;
    bf16x8 a[4];
    #pragma unroll
    for (int kk = 0; kk < 4; ++kk)
        a[kk] = *(const bf16x8*)(er + kk * 32);

    f32x4 acc[16];
    #pragma unroll
    for (int jt = 0; jt < 16; ++jt) acc[jt] = (f32x4){0.f, 0.f, 0.f, 0.f};

    #pragma unroll
    for (int kk = 0; kk < 4; ++kk) {
        #pragma unroll
        for (int jt = 0; jt < 16; ++jt) {
            bf16x8 b = *(const bf16x8*)(W1P + ((size_t)(jt * 4 + kk) * 64 + lane) * 8);
            acc[jt] = __builtin_amdgcn_mfma_f32_16x16x32_bf16(a[kk], b, acc[jt], 0, 0, 0);
        }
    }

    float bcol[16], gcol[16], ecol[16];
    #pragma unroll
    for (int jt = 0; jt < 16; ++jt) {
        bcol[jt] = b1[jt * 16 + m];
        gcol[jt] = g1[jt * 16 + m];
        ecol[jt] = be1[jt * 16 + m];
    }
    int base = nb + w * 16 + quad * 4;
    float4 dv4 = *(const float4*)&dinv[base < N ? base : 0];
    float dvr[4] = {dv4.x, dv4.y, dv4.z, dv4.w};

    #pragma unroll
    for (int reg = 0; reg < 4; ++reg) {
        int row = base + reg;
        float v[16];
        float s = 0.f, q = 0.f;
        #pragma unroll
        for (int jt = 0; jt < 16; ++jt) {
            float x = fmaxf(fmaf(acc[jt][reg], dvr[reg], bcol[jt]), 0.0f);
            v[jt] = x;
            s += x; q += x * x;
        }
        #pragma unroll
        for (int off = 1; off < 16; off <<= 1) {
            s += __shfl_xor(s, off);
            q += __shfl_xor(q, off);
        }
        float mu = s * (1.0f / 256.0f);
        float var = fmaxf(q * (1.0f / 256.0f) - mu * mu, 0.0f);
        float rstd = rsqrtf(var + 1e-5f);
        if (row < N) {
            unsigned short* xp = x1 + (size_t)row * 256 + m;
            #pragma unroll
            for (int jt = 0; jt < 16; ++jt)
                xp[jt * 16] = f2bf(fmaf((v[jt] - mu) * rstd, gcol[jt], ecol[jt]));
        }
    }
}

// GEMM2 (MFMA): h2s[n][j] = bf16( dinv[n] * sum_k x1[n][k] * W2[k][j] )
__global__ __launch_bounds__(256) void gemm2_k(
    const unsigned short* __restrict__ x1, const unsigned short* __restrict__ W2P,
    const float* __restrict__ dinv, unsigned short* __restrict__ h2s, int N)
{
    const int t = threadIdx.x;
    const int w = t >> 6;
    const int lane = t & 63;
    const int m = lane & 15;
    const int quad = lane >> 4;
    const int nb = blockIdx.x * 64;

    int node_a = nb + w * 16 + m;
    int idn = node_a < N ? node_a : N - 1;

    const unsigned short* er = x1 + (size_t)idn * 256 + quad * 8;
    bf16x8 a[8];
    #pragma unroll
    for (int kk = 0; kk < 8; ++kk)
        a[kk] = *(const bf16x8*)(er + kk * 32);

    f32x4 acc[8];
    #pragma unroll
    for (int jt = 0; jt < 8; ++jt) acc[jt] = (f32x4){0.f, 0.f, 0.f, 0.f};

    #pragma unroll
    for (int kk = 0; kk < 8; ++kk) {
        #pragma unroll
        for (int jt = 0; jt < 8; ++jt) {
            bf16x8 b = *(const bf16x8*)(W2P + ((size_t)(jt * 8 + kk) * 64 + lane) * 8);
            acc[jt] = __builtin_amdgcn_mfma_f32_16x16x32_bf16(a[kk], b, acc[jt], 0, 0, 0);
        }
    }

    int base = nb + w * 16 + quad * 4;
    float4 dv4 = *(const float4*)&dinv[base < N ? base : 0];
    float dvr[4] = {dv4.x, dv4.y, dv4.z, dv4.w};
    #pragma unroll
    for (int reg = 0; reg < 4; ++reg) {
        int node_r = base + reg;
        if (node_r < N) {
            unsigned short* hp = h2s + (size_t)node_r * 128 + m;
            #pragma unroll
            for (int jt = 0; jt < 8; ++jt)
                hp[jt * 16] = f2bf(acc[jt][reg] * dvr[reg]);
        }
    }
}

// fused gather-aggregate + LN layer 2; persistent grid-stride waves, final store
__global__ __launch_bounds__(256) void agg_ln2_k(
    const unsigned short* __restrict__ h2s, const int* __restrict__ offs,
    const int* __restrict__ cnt, const unsigned short* __restrict__ csr,
    const float* __restrict__ dinv, const float* __restrict__ b2,
    const float* __restrict__ g2, const float* __restrict__ be2,
    const int* __restrict__ flag, void* __restrict__ out, int N)
{
    int lane = threadIdx.x & 63;
    int wid = blockIdx.x * 4 + (threadIdx.x >> 6);
    int f = flag[0];

    for (int n = wid; n < N; n += AGG_WAVES) {
        float ax[8], ay[8];
        #pragma unroll
        for (int i = 0; i < 8; ++i) { ax[i] = 0.f; ay[i] = 0.f; }
        {
            unsigned int r = *(const unsigned int*)&h2s[(size_t)n * 128 + lane * 2];
            cvt2(r, ax[0], ay[0]);
        }
        int beg = offs[n];
        int end = beg + cnt[n];
        int j = beg;
        for (; j + 7 < end; j += 8) {
            unsigned int rr[8];
            #pragma unroll
            for (int i = 0; i < 8; ++i) {
                int s = csr[j + i];
                rr[i] = *(const unsigned int*)&h2s[(size_t)s * 128 + lane * 2];
            }
            #pragma unroll
            for (int i = 0; i < 8; ++i) {
                float v0, v1; cvt2(rr[i], v0, v1);
                ax[i] += v0; ay[i] += v1;
            }
        }
        for (; j + 1 < end; j += 2) {
            int s0 = csr[j], s1 = csr[j + 1];
            unsigned int r0 = *(const unsigned int*)&h2s[(size_t)s0 * 128 + lane * 2];
            unsigned int r1 = *(const unsigned int*)&h2s[(size_t)s1 * 128 + lane * 2];
            float v0, v1; cvt2(r0, v0, v1); ax[0] += v0; ay[0] += v1;
            cvt2(r1, v0, v1); ax[1] += v0; ay[1] += v1;
        }
        if (j < end) {
            int s0 = csr[j];
            unsigned int r0 = *(const unsigned int*)&h2s[(size_t)s0 * 128 + lane * 2];
            float v0, v1; cvt2(r0, v0, v1); ax[0] += v0; ay[0] += v1;
        }
        float sum0 = ((ax[0]+ax[1])+(ax[2]+ax[3])) + ((ax[4]+ax[5])+(ax[6]+ax[7]));
        float sum1 = ((ay[0]+ay[1])+(ay[2]+ay[3])) + ((ay[4]+ay[5])+(ay[6]+ay[7]));
        float dv = dinv[n];
        float2 bv = *(const float2*)&b2[lane * 2];
        float x0 = fmaf(sum0, dv, bv.x);
        float x1 = fmaf(sum1, dv, bv.y);
        float s = x0 + x1;
        float q = x0*x0 + x1*x1;
        #pragma unroll
        for (int off = 32; off > 0; off >>= 1) {
            s += __shfl_xor(s, off);
            q += __shfl_xor(q, off);
        }
        float mu = s * (1.0f / 128.0f);
        float var = fmaxf(q * (1.0f / 128.0f) - mu * mu, 0.0f);
        float rstd = rsqrtf(var + 1e-5f);
        float2 gv = *(const float2*)&g2[lane * 2];
        float2 ev = *(const float2*)&be2[lane * 2];
        float o0 = fmaf((x0 - mu) * rstd, gv.x, ev.x);
        float o1 = fmaf((x1 - mu) * rstd, gv.y, ev.y);
        if (f) {
            *(float2*)&((float*)out)[(size_t)n * 128 + lane * 2] = make_float2(o0, o1);
        } else {
            unsigned int packed = (unsigned int)f2bf(o0) | ((unsigned int)f2bf(o1) << 16);
            *(unsigned int*)&((unsigned short*)out)[(size_t)n * 128 + lane * 2] = packed;
        }
    }
}

extern "C" void kernel_launch(void* const* d_in, const int* in_sizes, int n_in,
                              void* d_out, int out_size, void* d_ws, size_t ws_size,
                              hipStream_t stream) {
    const int N = in_sizes[0];
    const int E = in_sizes[1] / 2;
    const int NB = (N + 255) / 256;

    const int* x_ids = (const int*)d_in[0];
    const int* src = (const int*)d_in[1];
    const int* dst = src + E;
    const void* embed = d_in[2];
    const void* W1 = d_in[3];
    const void* b1 = d_in[4];
    const void* g1 = d_in[5];
    const void* be1 = d_in[6];
    const void* W2 = d_in[7];
    const void* b2 = d_in[8];
    const void* g2 = d_in[9];
    const void* be2 = d_in[10];

    char* w = (char*)d_ws;
    auto take = [&](size_t bytes) { char* p = w; w += (bytes + 255) & ~(size_t)255; return p; };
    int* flag             = (int*)take(4);
    unsigned short* W1P   = (unsigned short*)take(65536);
    unsigned short* W2P   = (unsigned short*)take(65536);
    float* b1F  = (float*)take(1024);
    float* g1F  = (float*)take(1024);
    float* be1F = (float*)take(1024);
    float* b2F  = (float*)take(512);
    float* g2F  = (float*)take(512);
    float* be2F = (float*)take(512);
    int* bsum   = (int*)take(1024);
    int* boff   = (int*)take(1024);
    int* cnt    = (int*)take((size_t)N * 4);
    int* offs   = (int*)take((size_t)N * 4);
    int* cur    = (int*)take((size_t)N * 4);
    unsigned short* csr = (unsigned short*)take((size_t)E * 2);
    float* dinv = (float*)take(((size_t)N + 64) * 4);
    unsigned short* xs    = (unsigned short*)take((size_t)N * 128 * 2);
    unsigned short* agg1s = (unsigned short*)take((size_t)N * 128 * 2);
    unsigned short* x1    = (unsigned short*)take((size_t)N * 256 * 2);
    unsigned short* h2s   = agg1s;   // reuse after gemm_ln1 consumed agg1s

    zero_flag_k  <<<1, 64, 0, stream>>>(flag);
    detect_zero_k<<<16 + NB, 256, 0, stream>>>((const unsigned int*)embed, flag, cnt, N);
    pack_k       <<<33, 256, 0, stream>>>(W1, W2, b1, g1, be1, b2, g2, be2, flag,
                                          W1P, W2P, b1F, g1F, be1F, b2F, g2F, be2F);

    // CSR build
    hist_k    <<<(E + 255) / 256, 256, 0, stream>>>(dst, cnt, E);
    blocksum_k<<<NB, 256, 0, stream>>>(cnt, bsum, N);
    scan1_k   <<<1, 256, 0, stream>>>(bsum, boff, NB);
    scan2_k   <<<NB, 256, 0, stream>>>(cnt, boff, offs, cur, dinv, N);
    fill_k    <<<(E + 255) / 256, 256, 0, stream>>>(src, dst, cur, csr, E);

    // layer 1: scale -> aggregate (128 feats) -> GEMM+bias+ReLU+LN fused
    xs_k      <<<(N * 16 + 255) / 256, 256, 0, stream>>>(x_ids, embed, dinv, flag, xs, N);
    agg1_k    <<<AGG_WAVES / 4, 256, 0, stream>>>(xs, offs, cnt, csr, agg1s, N);
    gemm_ln1_k<<<(N + 63) / 64, 256, 0, stream>>>(agg1s, W1P, dinv, b1F, g1F, be1F, x1, N);

    // layer 2: GEMM -> aggregate + LN (final store)
    gemm2_k   <<<(N + 63) / 64, 256, 0, stream>>>(x1, W2P, dinv, h2s, N);
    agg_ln2_k <<<AGG_WAVES / 4, 256, 0, stream>>>(h2s, offs, cnt, csr, dinv, b2F, g2F, be2F, flag, d_out, N);
}